// Round 4
// baseline (402.360 us; speedup 1.0000x reference)
//
#include <hip/hip_runtime.h>
#include <hip/hip_bf16.h>
#include <math.h>

// ---- problem constants ----
#define NB 256      // batch
#define NN 307      // vertices
#define NBN 78592   // NB*NN
#define LL 12       // sequence length
#define DDIM 16     // model dim
#define HISW 268    // 267 history cols + 1 zero pad (for float4)
#define HIS4 67     // HISW/4
#define NBRCAP 128  // per-row neighbor capacity
#define AGRP 21     // bn rows per 256-thread block in attn (252 lanes active)
#define ADTS 308    // AdT row stride (padded even for float2 alignment)

// ---- workspace layout (float offsets; every segment 16B-aligned) ----
#define OFF_XTCN 0u            // 15089664 floats  [B,N,L,D]
#define OFF_G1   15089664u     //   943104 floats  [B,N,L]
#define OFF_ADT  16032768u     //    94688 floats  A_dyn^T [m][308]
#define OFF_TE   16127456u     //    49152 floats  [B,L,D]
#define OFF_HIS  16176608u     //    82288 floats  [N,268]
#define OFF_NW   16258896u     //    39296 floats  nbr weights [N,128]
#define OFF_NIDX 16298192u     //    39296 ints    nbr indices [N,128]
#define OFF_NCNT 16337488u     //      320 ints    nbr counts

__device__ inline float4 mkf4(float a, float b, float c, float d) {
    float4 r; r.x = a; r.y = b; r.z = c; r.w = d; return r;
}

// ---------------------------------------------------------------------------
// K0a: build padded history matrix his[N][268]
// ---------------------------------------------------------------------------
__global__ void his_kernel(const float* __restrict__ flow, float* __restrict__ his) {
    int e = blockIdx.x * 256 + threadIdx.x;
    if (e >= NN * HISW) return;
    int n = e / HISW, j = e - n * HISW;
    float v = 0.f;
    if (j < LL) v = flow[n * LL + j];
    else if (j < 267) v = flow[((j - 11) * NN + n) * LL + 11];
    his[e] = v;
}

// ---------------------------------------------------------------------------
// K0b: TE[b,l,d] = pos_enc + day_emb[day_cyc] + week_emb[week_cyc]
// ---------------------------------------------------------------------------
__global__ void te_kernel(const int* __restrict__ dayc, const int* __restrict__ weekc,
                          const float* __restrict__ demb, const float* __restrict__ wemb,
                          float* __restrict__ TE) {
    int e = blockIdx.x * 256 + threadIdx.x;
    if (e >= NB * LL * DDIM) return;
    int d = e & 15, l = (e >> 4) % LL, b = e / (LL * DDIM);
    int dc = dayc[b * LL + l], wc = weekc[b * LL + l];
    int i = d >> 1;
    float ang = (float)l * powf(10000.f, -0.125f * (float)i);
    float pe = (d & 1) ? cosf(ang) : sinf(ang);
    TE[e] = demb[dc * DDIM + d] + wemb[wc * DDIM + d] + pe;
}

// ---------------------------------------------------------------------------
// K1: A_dyn row-softmax of -dist, stored transposed AdT[m*308+n]
// ---------------------------------------------------------------------------
__global__ __launch_bounds__(256) void adyn_kernel(const float* __restrict__ his,
                                                   float* __restrict__ AdT) {
    __shared__ float4 sh[HIS4];
    __shared__ float red[256];
    int n = blockIdx.x, t = threadIdx.x;
    if (t < HIS4) sh[t] = reinterpret_cast<const float4*>(his)[n * HIS4 + t];
    __syncthreads();

    float e0 = 0.f, e1 = 0.f, lsum = 0.f;
    {
        const float4* row = reinterpret_cast<const float4*>(his) + t * HIS4;
        float4 acc = mkf4(0.f, 0.f, 0.f, 0.f);
        for (int j = 0; j < HIS4; j++) {
            float4 a = sh[j], b = row[j];
            float dx = a.x - b.x, dy = a.y - b.y, dz = a.z - b.z, dw = a.w - b.w;
            acc.x += dx * dx; acc.y += dy * dy; acc.z += dz * dz; acc.w += dw * dw;
        }
        float d2 = (acc.x + acc.y) + (acc.z + acc.w);
        e0 = __expf(-sqrtf(fmaxf(d2, 0.f)));
        lsum += e0;
    }
    int m1 = t + 256;
    if (m1 < NN) {
        const float4* row = reinterpret_cast<const float4*>(his) + m1 * HIS4;
        float4 acc = mkf4(0.f, 0.f, 0.f, 0.f);
        for (int j = 0; j < HIS4; j++) {
            float4 a = sh[j], b = row[j];
            float dx = a.x - b.x, dy = a.y - b.y, dz = a.z - b.z, dw = a.w - b.w;
            acc.x += dx * dx; acc.y += dy * dy; acc.z += dz * dz; acc.w += dw * dw;
        }
        float d2 = (acc.x + acc.y) + (acc.z + acc.w);
        e1 = __expf(-sqrtf(fmaxf(d2, 0.f)));
        lsum += e1;
    }
    red[t] = lsum;
    __syncthreads();
    for (int s = 128; s > 0; s >>= 1) {
        if (t < s) red[t] += red[t + s];
        __syncthreads();
    }
    float inv = 1.f / red[0];
    AdT[t * ADTS + n] = e0 * inv;
    if (m1 < NN) AdT[m1 * ADTS + n] = e1 * inv;
}

// ---------------------------------------------------------------------------
// K2: sparse A_st rows (ballot compaction)
// ---------------------------------------------------------------------------
__global__ __launch_bounds__(64) void nbr_kernel(const float* __restrict__ adj,
                                                 int* __restrict__ ncnt,
                                                 int* __restrict__ nidx,
                                                 float* __restrict__ nw) {
    int n = blockIdx.x, t = threadIdx.x;
    float rs = 0.f;
    for (int m0 = 0; m0 < NN; m0 += 64) {
        int m = m0 + t;
        if (m < NN) rs += adj[n * NN + m];
    }
    for (int off = 32; off > 0; off >>= 1) rs += __shfl_xor(rs, off);
    float inv = 1.f / (rs + 1.f);
    int c = 0;
    for (int m0 = 0; m0 < NN; m0 += 64) {
        int m = m0 + t;
        float a = (m < NN) ? adj[n * NN + m] : 0.f;
        bool p = (a != 0.f);
        unsigned long long mask = __ballot(p);
        int pos = __popcll(mask & ((1ull << t) - 1ull));
        if (p && (c + pos) < NBRCAP) {
            nidx[n * NBRCAP + c + pos] = m;
            nw[n * NBRCAP + c + pos] = a * inv;
        }
        c += (int)__popcll(mask);
    }
    if (t == 0) ncnt[n] = c < NBRCAP ? c : NBRCAP;
}

// ---------------------------------------------------------------------------
// K3 v4: temporal self-attention. 256 threads = 21 bn groups of 12 rows.
// Changes vs v3 (which ran 92us @ 19% occupancy, 50% VALUBusy, 45KB LDS):
//  - K,V stored in LDS as packed bf16 (rows padded to 24 ushorts for b128
//    writes): LDS 45KB -> ~28.5KB => ~5 blocks/CU (occupancy ~1.7x).
//    bf16 K/V error attenuates through Wo*Wt*W1*W2 (all ~0.02 scale) to
//    <1e-7 at the final output -- far below the 5.4e-5 threshold.
//  - Stage B reads K/V as uint2 (4 bf16 = 2 heads per read): 96 b64 reads
//    per lane instead of 192, halving stage-B LDS pipe pressure.
// ---------------------------------------------------------------------------
__global__ __launch_bounds__(256) void attn_kernel(
    const float* __restrict__ flow, const float* __restrict__ TE,
    const float* __restrict__ Wq, const float* __restrict__ bq,
    const float* __restrict__ Wk, const float* __restrict__ bk,
    const float* __restrict__ Wv, const float* __restrict__ bv,
    const float* __restrict__ Wo, const float* __restrict__ bo,
    float* __restrict__ xtcn) {
    __shared__ __align__(16) float sW[4][256];
    __shared__ __align__(16) float sBias[4][16];
    __shared__ __align__(16) unsigned short sKV[2][AGRP][LL][24];  // bf16, row pad 24

    const int t = threadIdx.x;
    // stage weights (1024 floats) + biases (64)
    for (int id = t; id < 1024; id += 256) {
        int mat = id >> 8, idx = id & 255;
        float v = (mat == 0) ? Wq[idx] : (mat == 1) ? Wk[idx] : (mat == 2) ? Wv[idx] : Wo[idx];
        sW[mat][idx] = v;
    }
    if (t < 64) {
        int mat = t >> 4, d = t & 15;
        sBias[mat][d] = (mat == 0) ? bq[d] : (mat == 1) ? bk[d] : (mat == 2) ? bv[d] : bo[d];
    }

    const int g = t / LL, l = t - g * LL;
    const int bn = blockIdx.x * AGRP + g;
    const bool act = (t < AGRP * LL) && (bn < NBN);

    float x[16];
    if (act) {
        const int b = bn / NN;
        float f = flow[bn * LL + l];
        const float4* te4 = reinterpret_cast<const float4*>(TE + (b * LL + l) * DDIM);
        float4 t0 = te4[0], t1 = te4[1], t2 = te4[2], t3 = te4[3];
        x[0] = f + t0.x; x[1] = f + t0.y; x[2] = f + t0.z; x[3] = f + t0.w;
        x[4] = f + t1.x; x[5] = f + t1.y; x[6] = f + t1.z; x[7] = f + t1.w;
        x[8] = f + t2.x; x[9] = f + t2.y; x[10] = f + t2.z; x[11] = f + t2.w;
        x[12] = f + t3.x; x[13] = f + t3.y; x[14] = f + t3.z; x[15] = f + t3.w;
    }
    __syncthreads();   // sW/sBias ready

    float q[16];
    if (act) {
        float k[16], v[16];
#pragma unroll
        for (int d = 0; d < 16; d++) {
            q[d] = sBias[0][d]; k[d] = sBias[1][d]; v[d] = sBias[2][d];
        }
#pragma unroll
        for (int e = 0; e < 16; e++) {
            float xe = x[e];
            const float4* wq = reinterpret_cast<const float4*>(&sW[0][e * 16]);
            const float4* wk = reinterpret_cast<const float4*>(&sW[1][e * 16]);
            const float4* wv = reinterpret_cast<const float4*>(&sW[2][e * 16]);
#pragma unroll
            for (int j = 0; j < 4; j++) {
                float4 a = wq[j];
                q[4 * j] += xe * a.x; q[4 * j + 1] += xe * a.y;
                q[4 * j + 2] += xe * a.z; q[4 * j + 3] += xe * a.w;
                float4 bb = wk[j];
                k[4 * j] += xe * bb.x; k[4 * j + 1] += xe * bb.y;
                k[4 * j + 2] += xe * bb.z; k[4 * j + 3] += xe * bb.w;
                float4 c = wv[j];
                v[4 * j] += xe * c.x; v[4 * j + 1] += xe * c.y;
                v[4 * j + 2] += xe * c.z; v[4 * j + 3] += xe * c.w;
            }
        }
        // pack k,v to bf16 (round-to-nearest via +0x8000) and store 2x uint4 each
        unsigned bk_[8], bv_[8];
#pragma unroll
        for (int j = 0; j < 8; j++) {
            unsigned u0 = __float_as_uint(k[2 * j]) + 0x8000u;
            unsigned u1 = __float_as_uint(k[2 * j + 1]) + 0x8000u;
            bk_[j] = (u0 >> 16) | (u1 & 0xffff0000u);
            unsigned w0 = __float_as_uint(v[2 * j]) + 0x8000u;
            unsigned w1 = __float_as_uint(v[2 * j + 1]) + 0x8000u;
            bv_[j] = (w0 >> 16) | (w1 & 0xffff0000u);
        }
        uint4* kd = reinterpret_cast<uint4*>(&sKV[0][g][l][0]);
        uint4* vd = reinterpret_cast<uint4*>(&sKV[1][g][l][0]);
        uint4 k0; k0.x = bk_[0]; k0.y = bk_[1]; k0.z = bk_[2]; k0.w = bk_[3];
        uint4 k1; k1.x = bk_[4]; k1.y = bk_[5]; k1.z = bk_[6]; k1.w = bk_[7];
        uint4 v0; v0.x = bv_[0]; v0.y = bv_[1]; v0.z = bv_[2]; v0.w = bv_[3];
        uint4 v1; v1.x = bv_[4]; v1.y = bv_[5]; v1.z = bv_[6]; v1.w = bv_[7];
        kd[0] = k0; kd[1] = k1;
        vd[0] = v0; vd[1] = v1;
    }
    __syncthreads();   // k,v visible

    if (act) {
        float att[16];
#pragma unroll
        for (int p = 0; p < 4; p++) {   // head pairs (2p, 2p+1)
            float qa = q[4 * p], qb = q[4 * p + 1];
            float qc = q[4 * p + 2], qd = q[4 * p + 3];
            float s0[LL], s1[LL];
            float sum0 = 0.f, sum1 = 0.f;
#pragma unroll
            for (int m = 0; m < LL; m++) {
                uint2 kk = *reinterpret_cast<const uint2*>(&sKV[0][g][m][4 * p]);
                float k0 = __uint_as_float(kk.x << 16);
                float k1 = __uint_as_float(kk.x & 0xffff0000u);
                float k2 = __uint_as_float(kk.y << 16);
                float k3 = __uint_as_float(kk.y & 0xffff0000u);
                s0[m] = __expf((qa * k0 + qb * k1) * 0.70710678118654752f);
                s1[m] = __expf((qc * k2 + qd * k3) * 0.70710678118654752f);
                sum0 += s0[m]; sum1 += s1[m];
            }
            float a00 = 0.f, a01 = 0.f, a10 = 0.f, a11 = 0.f;
#pragma unroll
            for (int m = 0; m < LL; m++) {
                uint2 vv = *reinterpret_cast<const uint2*>(&sKV[1][g][m][4 * p]);
                float v0 = __uint_as_float(vv.x << 16);
                float v1 = __uint_as_float(vv.x & 0xffff0000u);
                float v2 = __uint_as_float(vv.y << 16);
                float v3 = __uint_as_float(vv.y & 0xffff0000u);
                a00 += s0[m] * v0; a01 += s0[m] * v1;
                a10 += s1[m] * v2; a11 += s1[m] * v3;
            }
            float i0 = 1.f / sum0, i1 = 1.f / sum1;
            att[4 * p] = a00 * i0; att[4 * p + 1] = a01 * i0;
            att[4 * p + 2] = a10 * i1; att[4 * p + 3] = a11 * i1;
        }
        // out-projection + residual
        float o[16];
#pragma unroll
        for (int d = 0; d < 16; d++) o[d] = sBias[3][d];
#pragma unroll
        for (int e = 0; e < 16; e++) {
            float ae = att[e];
            const float4* wo = reinterpret_cast<const float4*>(&sW[3][e * 16]);
#pragma unroll
            for (int j = 0; j < 4; j++) {
                float4 w = wo[j];
                o[4 * j] += ae * w.x; o[4 * j + 1] += ae * w.y;
                o[4 * j + 2] += ae * w.z; o[4 * j + 3] += ae * w.w;
            }
        }
        float4* dst = reinterpret_cast<float4*>(xtcn) + (size_t)bn * 48 + l * 4;
#pragma unroll
        for (int j = 0; j < 4; j++) {
            dst[j] = mkf4(x[4 * j] + o[4 * j], x[4 * j + 1] + o[4 * j + 1],
                          x[4 * j + 2] + o[4 * j + 2], x[4 * j + 3] + o[4 * j + 3]);
        }
    }
}

// ---------------------------------------------------------------------------
// K4 v3: G1[b,:,:] = A_dyn @ flow[b]. Block = (b, 128-n tile); flow[b] staged
// in LDS; AdT read coalesced as float2. No atomics.
// ---------------------------------------------------------------------------
__global__ __launch_bounds__(256) void g1_kernel(const float* __restrict__ flow,
                                                 const float* __restrict__ AdT,
                                                 float* __restrict__ G1) {
    __shared__ float sflow[NN * LL];   // 3684 floats
    int b = blockIdx.x, nt = blockIdx.y, t = threadIdx.x;
    const float* fb = flow + (size_t)b * (NN * LL);
    for (int e = t; e < NN * LL; e += 256) sflow[e] = fb[e];
    __syncthreads();

    int lane = t & 63, lq = t >> 6;
    int n = nt * 128 + 2 * lane;
    int l0 = lq * 3;
    float a00 = 0.f, a01 = 0.f, a02 = 0.f, a10 = 0.f, a11 = 0.f, a12 = 0.f;
#pragma unroll 4
    for (int m = 0; m < NN; m++) {
        float2 w = reinterpret_cast<const float2*>(AdT + (size_t)m * ADTS + nt * 128)[lane];
        float f0 = sflow[m * LL + l0];
        float f1 = sflow[m * LL + l0 + 1];
        float f2 = sflow[m * LL + l0 + 2];
        a00 += w.x * f0; a01 += w.x * f1; a02 += w.x * f2;
        a10 += w.y * f0; a11 += w.y * f1; a12 += w.y * f2;
    }
    if (n < NN) {
        float* dst = G1 + ((size_t)b * NN + n) * LL + l0;
        dst[0] = a00; dst[1] = a01; dst[2] = a02;
    }
    if (n + 1 < NN) {
        float* dst = G1 + ((size_t)b * NN + n + 1) * LL + l0;
        dst[0] = a10; dst[1] = a11; dst[2] = a12;
    }
}

// ---------------------------------------------------------------------------
// K5 v3: fused graph-mix + per-vertex MLP. Block = (n, 4 batches); all
// per-n weights + Wt/Wg staged in LDS once. Wave w handles b = 4*blockIdx.y+w.
// ---------------------------------------------------------------------------
__global__ __launch_bounds__(256) void final_kernel(
    const float* __restrict__ xtcn, const float* __restrict__ G1,
    const float* __restrict__ Wg, const float* __restrict__ Wt,
    const float* __restrict__ bg, const float* __restrict__ W1,
    const float* __restrict__ b1, const float* __restrict__ W2,
    const float* __restrict__ b2, const int* __restrict__ ncnt,
    const int* __restrict__ nidx, const float* __restrict__ nw,
    float* __restrict__ out) {
    __shared__ __align__(16) float sWt[512];
    __shared__ __align__(16) float sW1[256];
    __shared__ __align__(16) float sWg[32];
    __shared__ __align__(16) float sBg[32];
    __shared__ float sB1[8], sW2[8];
    __shared__ __align__(16) float sY[4][192];
    __shared__ __align__(16) float4 sHID[4][96];
    __shared__ float sH1[4][96];

    int t = threadIdx.x;
    int n = blockIdx.x;
    int w = t >> 6, t64 = t & 63;
    int b = blockIdx.y * 4 + w;

    // stage weights
    sW1[t] = W1[n * 256 + t];
    sWt[t] = Wt[t];
    sWt[t + 256] = Wt[t + 256];
    if (t < 32) sWg[t] = Wg[t];
    else if (t < 64) sBg[t - 32] = bg[t - 32];
    else if (t < 72) sB1[t - 64] = b1[n * 8 + (t - 64)];
    else if (t < 80) sW2[t - 72] = W2[n * 8 + (t - 72)];
    float b2v = b2[n];
    int cnt = ncnt[n];
    __syncthreads();

    // sparse gather: y = sum_nbr w * xtcn[b, m, :]
    float y0 = 0.f, y1 = 0.f, y2 = 0.f;
    const float* base = xtcn + (size_t)b * NN * 192;
    int i = 0;
    for (; i + 1 < cnt; i += 2) {
        int ma = nidx[n * NBRCAP + i], mb = nidx[n * NBRCAP + i + 1];
        float wa = nw[n * NBRCAP + i], wb = nw[n * NBRCAP + i + 1];
        const float* sa = base + ma * 192;
        const float* sb = base + mb * 192;
        float p0 = sa[t64], p1 = sa[t64 + 64], p2 = sa[t64 + 128];
        float q0 = sb[t64], q1 = sb[t64 + 64], q2 = sb[t64 + 128];
        y0 += wa * p0 + wb * q0; y1 += wa * p1 + wb * q1; y2 += wa * p2 + wb * q2;
    }
    if (i < cnt) {
        int ma = nidx[n * NBRCAP + i];
        float wa = nw[n * NBRCAP + i];
        const float* sa = base + ma * 192;
        y0 += wa * sa[t64]; y1 += wa * sa[t64 + 64]; y2 += wa * sa[t64 + 128];
    }
    sY[w][t64] = y0; sY[w][t64 + 64] = y1; sY[w][t64 + 128] = y2;
    __syncthreads();

    // hid = relu(G1*Wg + y@Wt + bg)  -> sHID[w][96] float4 chunks
#pragma unroll
    for (int p = 0; p < 2; p++) {
        int c = t64 + p * 64;
        if (c < 96) {
            int l = c >> 3, j = c & 7;
            float g = G1[((size_t)b * NN + n) * LL + l];
            float4 wg = reinterpret_cast<const float4*>(sWg)[j];
            float4 acc = reinterpret_cast<const float4*>(sBg)[j];
            acc.x += g * wg.x; acc.y += g * wg.y; acc.z += g * wg.z; acc.w += g * wg.w;
            const float4* yr = reinterpret_cast<const float4*>(&sY[w][l * 16]);
            float4 v0 = yr[0], v1 = yr[1], v2 = yr[2], v3 = yr[3];
            float ye[16] = {v0.x, v0.y, v0.z, v0.w, v1.x, v1.y, v1.z, v1.w,
                            v2.x, v2.y, v2.z, v2.w, v3.x, v3.y, v3.z, v3.w};
#pragma unroll
            for (int d = 0; d < 16; d++) {
                float4 wt = reinterpret_cast<const float4*>(sWt)[d * 8 + j];
                acc.x += ye[d] * wt.x; acc.y += ye[d] * wt.y;
                acc.z += ye[d] * wt.z; acc.w += ye[d] * wt.w;
            }
            acc.x = fmaxf(acc.x, 0.f); acc.y = fmaxf(acc.y, 0.f);
            acc.z = fmaxf(acc.z, 0.f); acc.w = fmaxf(acc.w, 0.f);
            sHID[w][c] = acc;
        }
    }
    __syncthreads();

    // h1 = relu(hid @ W1[n] + b1[n])
#pragma unroll
    for (int p = 0; p < 2; p++) {
        int o = t64 + p * 64;
        if (o < 96) {
            int l = o >> 3, oo = o & 7;
            float acc = sB1[oo];
            float he[32];
#pragma unroll
            for (int k = 0; k < 8; k++) {
                float4 hv = sHID[w][l * 8 + k];
                he[4 * k + 0] = hv.x; he[4 * k + 1] = hv.y;
                he[4 * k + 2] = hv.z; he[4 * k + 3] = hv.w;
            }
#pragma unroll
            for (int c = 0; c < 32; c++) acc += he[c] * sW1[c * 8 + oo];
            sH1[w][o] = fmaxf(acc, 0.f);
        }
    }
    __syncthreads();

    // out = h1 @ W2[n] + b2[n]
    if (t64 < LL) {
        float acc = b2v;
#pragma unroll
        for (int o = 0; o < 8; o++) acc += sH1[w][t64 * 8 + o] * sW2[o];
        out[((size_t)b * NN + n) * LL + t64] = acc;
    }
}

// ---------------------------------------------------------------------------
extern "C" void kernel_launch(void* const* d_in, const int* in_sizes, int n_in,
                              void* d_out, int out_size, void* d_ws, size_t ws_size,
                              hipStream_t stream) {
    const float* flow = (const float*)d_in[0];
    const int* dayc   = (const int*)d_in[1];
    const int* weekc  = (const int*)d_in[2];
    const float* adj  = (const float*)d_in[3];
    const float* demb = (const float*)d_in[4];
    const float* wemb = (const float*)d_in[5];
    const float* Wq = (const float*)d_in[6];  const float* bq = (const float*)d_in[7];
    const float* Wk = (const float*)d_in[8];  const float* bk = (const float*)d_in[9];
    const float* Wv = (const float*)d_in[10]; const float* bv = (const float*)d_in[11];
    const float* Wo = (const float*)d_in[12]; const float* bo = (const float*)d_in[13];
    const float* Wg = (const float*)d_in[14]; const float* Wt = (const float*)d_in[15];
    const float* bg = (const float*)d_in[16];
    const float* W1 = (const float*)d_in[17]; const float* b1 = (const float*)d_in[18];
    const float* W2 = (const float*)d_in[19]; const float* b2 = (const float*)d_in[20];
    float* out = (float*)d_out;
    float* ws  = (float*)d_ws;

    float* xtcn = ws + OFF_XTCN;
    float* G1   = ws + OFF_G1;
    float* AdT  = ws + OFF_ADT;
    float* TE   = ws + OFF_TE;
    float* his  = ws + OFF_HIS;
    float* nw   = ws + OFF_NW;
    int*   nidx = (int*)(ws + OFF_NIDX);
    int*   ncnt = (int*)(ws + OFF_NCNT);

    his_kernel<<<(NN * HISW + 255) / 256, 256, 0, stream>>>(flow, his);
    te_kernel<<<(NB * LL * DDIM + 255) / 256, 256, 0, stream>>>(dayc, weekc, demb, wemb, TE);
    adyn_kernel<<<NN, 256, 0, stream>>>(his, AdT);
    nbr_kernel<<<NN, 64, 0, stream>>>(adj, ncnt, nidx, nw);
    attn_kernel<<<(NBN + AGRP - 1) / AGRP, 256, 0, stream>>>(flow, TE, Wq, bq, Wk, bk,
                                                             Wv, bv, Wo, bo, xtcn);
    g1_kernel<<<dim3(NB, 3), 256, 0, stream>>>(flow, AdT, G1);
    final_kernel<<<dim3(NN, 64), 256, 0, stream>>>(xtcn, G1, Wg, Wt, bg, W1, b1, W2, b2,
                                                   ncnt, nidx, nw, out);
}

// Round 5
// 293.655 us; speedup vs baseline: 1.3702x; 1.3702x over previous
//
#include <hip/hip_runtime.h>
#include <hip/hip_bf16.h>
#include <math.h>

// ---- problem constants ----
#define NB 256      // batch
#define NN 307      // vertices
#define NBN 78592   // NB*NN
#define LL 12       // sequence length
#define DDIM 16     // model dim
#define HISW 268    // 267 history cols + 1 zero pad (for float4)
#define HIS4 67     // HISW/4
#define NBRCAP 64   // per-row neighbor capacity (mean 9.2, 64 is ~18 sigma)
#define AGRP 15     // bn rows per 192-thread block in attn (180 lanes active)
#define ADTS 308    // AdT row stride (padded even for float2 alignment)

// ---- workspace layout (float offsets; every segment 16B-aligned) ----
#define OFF_XTCN 0u            // 15089664 floats  [B,N,L,D]
#define OFF_G1   15089664u     //   943104 floats  [B,N,L]
#define OFF_ADT  16032768u     //    94688 floats  A_dyn^T [m][308]
#define OFF_TEQ  16127456u     //    49152 floats  [B,L,16]  (te@Wq+bq)/sqrt2
#define OFF_HIS  16176608u     //    82288 floats  [N,268]; TEK overlays (adyn first)
#define OFF_TEK  16176608u     //    49152 floats  te@Wk+bk   (aliases HIS)
#define OFF_NW   16258896u     //    19648 floats  nbr weights [N,64]
#define OFF_NIDX 16278544u     //    19648 ints    nbr indices [N,64]
#define OFF_NCNT 16298192u     //      320 ints    nbr counts
#define OFF_TEV  16298512u     //    49152 floats  te@Wv+bv
#define OFF_TEO  16347664u     //    49152 floats  te+bo

__device__ inline float4 mkf4(float a, float b, float c, float d) {
    float4 r; r.x = a; r.y = b; r.z = c; r.w = d; return r;
}

// ---------------------------------------------------------------------------
// K0a: build padded history matrix his[N][268]
// ---------------------------------------------------------------------------
__global__ void his_kernel(const float* __restrict__ flow, float* __restrict__ his) {
    int e = blockIdx.x * 256 + threadIdx.x;
    if (e >= NN * HISW) return;
    int n = e / HISW, j = e - n * HISW;
    float v = 0.f;
    if (j < LL) v = flow[n * LL + j];
    else if (j < 267) v = flow[((j - 11) * NN + n) * LL + 11];
    his[e] = v;
}

// ---------------------------------------------------------------------------
// K0b v2: TE tables. Row (b,l): te = pe + day_emb + week_emb, then
//   TEQ = (te@Wq+bq)/sqrt2, TEK = te@Wk+bk, TEV = te@Wv+bv, TEO = te+bo.
// Shared across all 307 vertices -> attn's per-row projection is 16 FMA.
// ---------------------------------------------------------------------------
__global__ __launch_bounds__(256) void te_kernel(
    const int* __restrict__ dayc, const int* __restrict__ weekc,
    const float* __restrict__ demb, const float* __restrict__ wemb,
    const float* __restrict__ Wq, const float* __restrict__ bq,
    const float* __restrict__ Wk, const float* __restrict__ bk,
    const float* __restrict__ Wv, const float* __restrict__ bv,
    const float* __restrict__ bo,
    float* __restrict__ TEQ, float* __restrict__ TEK,
    float* __restrict__ TEV, float* __restrict__ TEO) {
    __shared__ float sTE[16][16];
    int t = threadIdx.x, r = t >> 4, d = t & 15;
    int row = blockIdx.x * 16 + r;            // row < NB*LL = 3072
    int b = row / LL, l = row - b * LL;
    int dc = dayc[b * LL + l], wc = weekc[b * LL + l];
    int i = d >> 1;
    float ang = (float)l * powf(10000.f, -0.125f * (float)i);
    float pe = (d & 1) ? cosf(ang) : sinf(ang);
    float te = demb[dc * DDIM + d] + wemb[wc * DDIM + d] + pe;
    sTE[r][d] = te;
    __syncthreads();
    float aq = bq[d], ak = bk[d], av = bv[d];
#pragma unroll
    for (int e = 0; e < 16; e++) {
        float x = sTE[r][e];
        aq += x * Wq[e * 16 + d];
        ak += x * Wk[e * 16 + d];
        av += x * Wv[e * 16 + d];
    }
    TEQ[row * 16 + d] = aq * 0.70710678118654752f;
    TEK[row * 16 + d] = ak;
    TEV[row * 16 + d] = av;
    TEO[row * 16 + d] = te + bo[d];
}

// ---------------------------------------------------------------------------
// K1: A_dyn row-softmax of -dist, stored transposed AdT[m*308+n]
// ---------------------------------------------------------------------------
__global__ __launch_bounds__(256) void adyn_kernel(const float* __restrict__ his,
                                                   float* __restrict__ AdT) {
    __shared__ float4 sh[HIS4];
    __shared__ float red[256];
    int n = blockIdx.x, t = threadIdx.x;
    if (t < HIS4) sh[t] = reinterpret_cast<const float4*>(his)[n * HIS4 + t];
    __syncthreads();

    float e0 = 0.f, e1 = 0.f, lsum = 0.f;
    {
        const float4* row = reinterpret_cast<const float4*>(his) + t * HIS4;
        float4 acc = mkf4(0.f, 0.f, 0.f, 0.f);
        for (int j = 0; j < HIS4; j++) {
            float4 a = sh[j], b = row[j];
            float dx = a.x - b.x, dy = a.y - b.y, dz = a.z - b.z, dw = a.w - b.w;
            acc.x += dx * dx; acc.y += dy * dy; acc.z += dz * dz; acc.w += dw * dw;
        }
        float d2 = (acc.x + acc.y) + (acc.z + acc.w);
        e0 = __expf(-sqrtf(fmaxf(d2, 0.f)));
        lsum += e0;
    }
    int m1 = t + 256;
    if (m1 < NN) {
        const float4* row = reinterpret_cast<const float4*>(his) + m1 * HIS4;
        float4 acc = mkf4(0.f, 0.f, 0.f, 0.f);
        for (int j = 0; j < HIS4; j++) {
            float4 a = sh[j], b = row[j];
            float dx = a.x - b.x, dy = a.y - b.y, dz = a.z - b.z, dw = a.w - b.w;
            acc.x += dx * dx; acc.y += dy * dy; acc.z += dz * dz; acc.w += dw * dw;
        }
        float d2 = (acc.x + acc.y) + (acc.z + acc.w);
        e1 = __expf(-sqrtf(fmaxf(d2, 0.f)));
        lsum += e1;
    }
    red[t] = lsum;
    __syncthreads();
    for (int s = 128; s > 0; s >>= 1) {
        if (t < s) red[t] += red[t + s];
        __syncthreads();
    }
    float inv = 1.f / red[0];
    AdT[t * ADTS + n] = e0 * inv;
    if (m1 < NN) AdT[m1 * ADTS + n] = e1 * inv;
}

// ---------------------------------------------------------------------------
// K2: sparse A_st rows (ballot compaction)
// ---------------------------------------------------------------------------
__global__ __launch_bounds__(64) void nbr_kernel(const float* __restrict__ adj,
                                                 int* __restrict__ ncnt,
                                                 int* __restrict__ nidx,
                                                 float* __restrict__ nw) {
    int n = blockIdx.x, t = threadIdx.x;
    float rs = 0.f;
    for (int m0 = 0; m0 < NN; m0 += 64) {
        int m = m0 + t;
        if (m < NN) rs += adj[n * NN + m];
    }
    for (int off = 32; off > 0; off >>= 1) rs += __shfl_xor(rs, off);
    float inv = 1.f / (rs + 1.f);
    int c = 0;
    for (int m0 = 0; m0 < NN; m0 += 64) {
        int m = m0 + t;
        float a = (m < NN) ? adj[n * NN + m] : 0.f;
        bool p = (a != 0.f);
        unsigned long long mask = __ballot(p);
        int pos = __popcll(mask & ((1ull << t) - 1ull));
        if (p && (c + pos) < NBRCAP) {
            nidx[n * NBRCAP + c + pos] = m;
            nw[n * NBRCAP + c + pos] = a * inv;
        }
        c += (int)__popcll(mask);
    }
    if (t == 0) ncnt[n] = c < NBRCAP ? c : NBRCAP;
}

// ---------------------------------------------------------------------------
// K3 v5: temporal self-attention with TE-table algebra.
//   q = f*wq1 + TEQ[b,l],  k = f*wk1 + TEK,  v = f*wv1 + TEV
// (wq1/wk1/wv1 = column sums of W, computed per block: 48 lanes x 16 loads).
// 192 threads = 15 bn groups of 12 rows (180 active). K/V in f32 LDS
// (v3-proven stage B, 0 bank conflicts). LDS ~30KB -> 5 blocks/CU.
// Per-lane VALU ~900 (was ~1700 in v3).
// ---------------------------------------------------------------------------
__global__ __launch_bounds__(192, 5) void attn_kernel(
    const float* __restrict__ flow,
    const float* __restrict__ TEQ, const float* __restrict__ TEK,
    const float* __restrict__ TEV, const float* __restrict__ TEO,
    const float* __restrict__ Wq, const float* __restrict__ Wk,
    const float* __restrict__ Wv, const float* __restrict__ Wo,
    float* __restrict__ xtcn) {
    __shared__ __align__(16) float sWo[256];
    __shared__ __align__(16) float sWs[48];   // [0..15]=wq1/sqrt2, [16..31]=wk1, [32..47]=wv1
    __shared__ __align__(16) float sKV[2][AGRP][LL][20];

    const int t = threadIdx.x;
    for (int id = t; id < 256; id += 192) sWo[id] = Wo[id];
    if (t < 48) {
        int mat = t >> 4, d = t & 15;
        const float* W = (mat == 0) ? Wq : (mat == 1) ? Wk : Wv;
        float s = 0.f;
#pragma unroll
        for (int e = 0; e < 16; e++) s += W[e * 16 + d];
        sWs[t] = (mat == 0) ? s * 0.70710678118654752f : s;
    }

    const int g = t / LL, l = t - g * LL;
    const int bn = blockIdx.x * AGRP + g;
    const bool act = (t < AGRP * LL) && (bn < NBN);

    float f = 0.f;
    float tq[16], tk[16], tv[16];
    int row = 0;
    if (act) {
        const int b = bn / NN;
        row = b * LL + l;
        f = flow[bn * LL + l];
        const float4* q4 = reinterpret_cast<const float4*>(TEQ + row * 16);
        const float4* k4 = reinterpret_cast<const float4*>(TEK + row * 16);
        const float4* v4 = reinterpret_cast<const float4*>(TEV + row * 16);
#pragma unroll
        for (int j = 0; j < 4; j++) {
            float4 a = q4[j]; tq[4 * j] = a.x; tq[4 * j + 1] = a.y; tq[4 * j + 2] = a.z; tq[4 * j + 3] = a.w;
            float4 bb = k4[j]; tk[4 * j] = bb.x; tk[4 * j + 1] = bb.y; tk[4 * j + 2] = bb.z; tk[4 * j + 3] = bb.w;
            float4 c = v4[j]; tv[4 * j] = c.x; tv[4 * j + 1] = c.y; tv[4 * j + 2] = c.z; tv[4 * j + 3] = c.w;
        }
    }
    __syncthreads();   // sWo/sWs ready

    float q[16];
    if (act) {
        float k[16], v[16];
        const float4* ws4 = reinterpret_cast<const float4*>(sWs);
#pragma unroll
        for (int j = 0; j < 4; j++) {
            float4 wq = ws4[j], wk = ws4[4 + j], wv = ws4[8 + j];
            q[4 * j] = tq[4 * j] + f * wq.x;       q[4 * j + 1] = tq[4 * j + 1] + f * wq.y;
            q[4 * j + 2] = tq[4 * j + 2] + f * wq.z; q[4 * j + 3] = tq[4 * j + 3] + f * wq.w;
            k[4 * j] = tk[4 * j] + f * wk.x;       k[4 * j + 1] = tk[4 * j + 1] + f * wk.y;
            k[4 * j + 2] = tk[4 * j + 2] + f * wk.z; k[4 * j + 3] = tk[4 * j + 3] + f * wk.w;
            v[4 * j] = tv[4 * j] + f * wv.x;       v[4 * j + 1] = tv[4 * j + 1] + f * wv.y;
            v[4 * j + 2] = tv[4 * j + 2] + f * wv.z; v[4 * j + 3] = tv[4 * j + 3] + f * wv.w;
        }
        float4* kd = reinterpret_cast<float4*>(&sKV[0][g][l][0]);
        float4* vd = reinterpret_cast<float4*>(&sKV[1][g][l][0]);
#pragma unroll
        for (int j = 0; j < 4; j++) {
            kd[j] = mkf4(k[4 * j], k[4 * j + 1], k[4 * j + 2], k[4 * j + 3]);
            vd[j] = mkf4(v[4 * j], v[4 * j + 1], v[4 * j + 2], v[4 * j + 3]);
        }
    }
    __syncthreads();   // k,v visible

    if (act) {
        float att[16];
#pragma unroll
        for (int h = 0; h < 8; h++) {
            float qx = q[2 * h], qy = q[2 * h + 1];
            float s[LL];
            float sum = 0.f;
#pragma unroll
            for (int m = 0; m < LL; m++) {
                float2 kk = *reinterpret_cast<const float2*>(&sKV[0][g][m][2 * h]);
                s[m] = __expf(qx * kk.x + qy * kk.y);   // 1/sqrt2 folded into q
                sum += s[m];
            }
            float a0 = 0.f, a1 = 0.f;
#pragma unroll
            for (int m = 0; m < LL; m++) {
                float2 vv = *reinterpret_cast<const float2*>(&sKV[1][g][m][2 * h]);
                a0 += s[m] * vv.x; a1 += s[m] * vv.y;
            }
            float inv = 1.f / sum;
            att[2 * h] = a0 * inv; att[2 * h + 1] = a1 * inv;
        }
        // o = TEO[b,l] + att@Wo; out = o + f   (residual+bias folded into TEO)
        float o[16];
        const float4* to4 = reinterpret_cast<const float4*>(TEO + row * 16);
#pragma unroll
        for (int j = 0; j < 4; j++) {
            float4 a = to4[j];
            o[4 * j] = a.x; o[4 * j + 1] = a.y; o[4 * j + 2] = a.z; o[4 * j + 3] = a.w;
        }
#pragma unroll
        for (int e = 0; e < 16; e++) {
            float ae = att[e];
            const float4* wo = reinterpret_cast<const float4*>(&sWo[e * 16]);
#pragma unroll
            for (int j = 0; j < 4; j++) {
                float4 w = wo[j];
                o[4 * j] += ae * w.x; o[4 * j + 1] += ae * w.y;
                o[4 * j + 2] += ae * w.z; o[4 * j + 3] += ae * w.w;
            }
        }
        float4* dst = reinterpret_cast<float4*>(xtcn) + (size_t)bn * 48 + l * 4;
#pragma unroll
        for (int j = 0; j < 4; j++) {
            dst[j] = mkf4(o[4 * j] + f, o[4 * j + 1] + f, o[4 * j + 2] + f, o[4 * j + 3] + f);
        }
    }
}

// ---------------------------------------------------------------------------
// K4 v3: G1[b,:,:] = A_dyn @ flow[b]. Block = (b, 128-n tile); flow[b] staged
// in LDS; AdT read coalesced as float2. No atomics.
// ---------------------------------------------------------------------------
__global__ __launch_bounds__(256) void g1_kernel(const float* __restrict__ flow,
                                                 const float* __restrict__ AdT,
                                                 float* __restrict__ G1) {
    __shared__ float sflow[NN * LL];   // 3684 floats
    int b = blockIdx.x, nt = blockIdx.y, t = threadIdx.x;
    const float* fb = flow + (size_t)b * (NN * LL);
    for (int e = t; e < NN * LL; e += 256) sflow[e] = fb[e];
    __syncthreads();

    int lane = t & 63, lq = t >> 6;
    int n = nt * 128 + 2 * lane;
    int l0 = lq * 3;
    float a00 = 0.f, a01 = 0.f, a02 = 0.f, a10 = 0.f, a11 = 0.f, a12 = 0.f;
#pragma unroll 4
    for (int m = 0; m < NN; m++) {
        float2 w = reinterpret_cast<const float2*>(AdT + (size_t)m * ADTS + nt * 128)[lane];
        float f0 = sflow[m * LL + l0];
        float f1 = sflow[m * LL + l0 + 1];
        float f2 = sflow[m * LL + l0 + 2];
        a00 += w.x * f0; a01 += w.x * f1; a02 += w.x * f2;
        a10 += w.y * f0; a11 += w.y * f1; a12 += w.y * f2;
    }
    if (n < NN) {
        float* dst = G1 + ((size_t)b * NN + n) * LL + l0;
        dst[0] = a00; dst[1] = a01; dst[2] = a02;
    }
    if (n + 1 < NN) {
        float* dst = G1 + ((size_t)b * NN + n + 1) * LL + l0;
        dst[0] = a10; dst[1] = a11; dst[2] = a12;
    }
}

// ---------------------------------------------------------------------------
// K5 v3: fused graph-mix + per-vertex MLP. Block = (n, 4 batches); all
// per-n weights + Wt/Wg staged in LDS once. Wave w handles b = 4*blockIdx.y+w.
// ---------------------------------------------------------------------------
__global__ __launch_bounds__(256) void final_kernel(
    const float* __restrict__ xtcn, const float* __restrict__ G1,
    const float* __restrict__ Wg, const float* __restrict__ Wt,
    const float* __restrict__ bg, const float* __restrict__ W1,
    const float* __restrict__ b1, const float* __restrict__ W2,
    const float* __restrict__ b2, const int* __restrict__ ncnt,
    const int* __restrict__ nidx, const float* __restrict__ nw,
    float* __restrict__ out) {
    __shared__ __align__(16) float sWt[512];
    __shared__ __align__(16) float sW1[256];
    __shared__ __align__(16) float sWg[32];
    __shared__ __align__(16) float sBg[32];
    __shared__ float sB1[8], sW2[8];
    __shared__ __align__(16) float sY[4][192];
    __shared__ __align__(16) float4 sHID[4][96];
    __shared__ float sH1[4][96];

    int t = threadIdx.x;
    int n = blockIdx.x;
    int w = t >> 6, t64 = t & 63;
    int b = blockIdx.y * 4 + w;

    // stage weights
    sW1[t] = W1[n * 256 + t];
    sWt[t] = Wt[t];
    sWt[t + 256] = Wt[t + 256];
    if (t < 32) sWg[t] = Wg[t];
    else if (t < 64) sBg[t - 32] = bg[t - 32];
    else if (t < 72) sB1[t - 64] = b1[n * 8 + (t - 64)];
    else if (t < 80) sW2[t - 72] = W2[n * 8 + (t - 72)];
    float b2v = b2[n];
    int cnt = ncnt[n];
    __syncthreads();

    // sparse gather: y = sum_nbr w * xtcn[b, m, :]
    float y0 = 0.f, y1 = 0.f, y2 = 0.f;
    const float* base = xtcn + (size_t)b * NN * 192;
    int i = 0;
    for (; i + 1 < cnt; i += 2) {
        int ma = nidx[n * NBRCAP + i], mb = nidx[n * NBRCAP + i + 1];
        float wa = nw[n * NBRCAP + i], wb = nw[n * NBRCAP + i + 1];
        const float* sa = base + ma * 192;
        const float* sb = base + mb * 192;
        float p0 = sa[t64], p1 = sa[t64 + 64], p2 = sa[t64 + 128];
        float q0 = sb[t64], q1 = sb[t64 + 64], q2 = sb[t64 + 128];
        y0 += wa * p0 + wb * q0; y1 += wa * p1 + wb * q1; y2 += wa * p2 + wb * q2;
    }
    if (i < cnt) {
        int ma = nidx[n * NBRCAP + i];
        float wa = nw[n * NBRCAP + i];
        const float* sa = base + ma * 192;
        y0 += wa * sa[t64]; y1 += wa * sa[t64 + 64]; y2 += wa * sa[t64 + 128];
    }
    sY[w][t64] = y0; sY[w][t64 + 64] = y1; sY[w][t64 + 128] = y2;
    __syncthreads();

    // hid = relu(G1*Wg + y@Wt + bg)  -> sHID[w][96] float4 chunks
#pragma unroll
    for (int p = 0; p < 2; p++) {
        int c = t64 + p * 64;
        if (c < 96) {
            int l = c >> 3, j = c & 7;
            float g = G1[((size_t)b * NN + n) * LL + l];
            float4 wg = reinterpret_cast<const float4*>(sWg)[j];
            float4 acc = reinterpret_cast<const float4*>(sBg)[j];
            acc.x += g * wg.x; acc.y += g * wg.y; acc.z += g * wg.z; acc.w += g * wg.w;
            const float4* yr = reinterpret_cast<const float4*>(&sY[w][l * 16]);
            float4 v0 = yr[0], v1 = yr[1], v2 = yr[2], v3 = yr[3];
            float ye[16] = {v0.x, v0.y, v0.z, v0.w, v1.x, v1.y, v1.z, v1.w,
                            v2.x, v2.y, v2.z, v2.w, v3.x, v3.y, v3.z, v3.w};
#pragma unroll
            for (int d = 0; d < 16; d++) {
                float4 wt = reinterpret_cast<const float4*>(sWt)[d * 8 + j];
                acc.x += ye[d] * wt.x; acc.y += ye[d] * wt.y;
                acc.z += ye[d] * wt.z; acc.w += ye[d] * wt.w;
            }
            acc.x = fmaxf(acc.x, 0.f); acc.y = fmaxf(acc.y, 0.f);
            acc.z = fmaxf(acc.z, 0.f); acc.w = fmaxf(acc.w, 0.f);
            sHID[w][c] = acc;
        }
    }
    __syncthreads();

    // h1 = relu(hid @ W1[n] + b1[n])
#pragma unroll
    for (int p = 0; p < 2; p++) {
        int o = t64 + p * 64;
        if (o < 96) {
            int l = o >> 3, oo = o & 7;
            float acc = sB1[oo];
            float he[32];
#pragma unroll
            for (int k = 0; k < 8; k++) {
                float4 hv = sHID[w][l * 8 + k];
                he[4 * k + 0] = hv.x; he[4 * k + 1] = hv.y;
                he[4 * k + 2] = hv.z; he[4 * k + 3] = hv.w;
            }
#pragma unroll
            for (int c = 0; c < 32; c++) acc += he[c] * sW1[c * 8 + oo];
            sH1[w][o] = fmaxf(acc, 0.f);
        }
    }
    __syncthreads();

    // out = h1 @ W2[n] + b2[n]
    if (t64 < LL) {
        float acc = b2v;
#pragma unroll
        for (int o = 0; o < 8; o++) acc += sH1[w][t64 * 8 + o] * sW2[o];
        out[((size_t)b * NN + n) * LL + t64] = acc;
    }
}

// ---------------------------------------------------------------------------
extern "C" void kernel_launch(void* const* d_in, const int* in_sizes, int n_in,
                              void* d_out, int out_size, void* d_ws, size_t ws_size,
                              hipStream_t stream) {
    const float* flow = (const float*)d_in[0];
    const int* dayc   = (const int*)d_in[1];
    const int* weekc  = (const int*)d_in[2];
    const float* adj  = (const float*)d_in[3];
    const float* demb = (const float*)d_in[4];
    const float* wemb = (const float*)d_in[5];
    const float* Wq = (const float*)d_in[6];  const float* bq = (const float*)d_in[7];
    const float* Wk = (const float*)d_in[8];  const float* bk = (const float*)d_in[9];
    const float* Wv = (const float*)d_in[10]; const float* bv = (const float*)d_in[11];
    const float* Wo = (const float*)d_in[12]; const float* bo = (const float*)d_in[13];
    const float* Wg = (const float*)d_in[14]; const float* Wt = (const float*)d_in[15];
    const float* bg = (const float*)d_in[16];
    const float* W1 = (const float*)d_in[17]; const float* b1 = (const float*)d_in[18];
    const float* W2 = (const float*)d_in[19]; const float* b2 = (const float*)d_in[20];
    float* out = (float*)d_out;
    float* ws  = (float*)d_ws;

    float* xtcn = ws + OFF_XTCN;
    float* G1   = ws + OFF_G1;
    float* AdT  = ws + OFF_ADT;
    float* TEQ  = ws + OFF_TEQ;
    float* TEK  = ws + OFF_TEK;   // overlays his (adyn runs first)
    float* TEV  = ws + OFF_TEV;
    float* TEO  = ws + OFF_TEO;
    float* his  = ws + OFF_HIS;
    float* nw   = ws + OFF_NW;
    int*   nidx = (int*)(ws + OFF_NIDX);
    int*   ncnt = (int*)(ws + OFF_NCNT);

    // his -> adyn first (TEK overlays the his buffer afterwards)
    his_kernel<<<(NN * HISW + 255) / 256, 256, 0, stream>>>(flow, his);
    adyn_kernel<<<NN, 256, 0, stream>>>(his, AdT);
    te_kernel<<<(NB * LL) / 16, 256, 0, stream>>>(dayc, weekc, demb, wemb,
                                                  Wq, bq, Wk, bk, Wv, bv, bo,
                                                  TEQ, TEK, TEV, TEO);
    nbr_kernel<<<NN, 64, 0, stream>>>(adj, ncnt, nidx, nw);
    attn_kernel<<<(NBN + AGRP - 1) / AGRP, 192, 0, stream>>>(flow, TEQ, TEK, TEV, TEO,
                                                             Wq, Wk, Wv, Wo, xtcn);
    g1_kernel<<<dim3(NB, 3), 256, 0, stream>>>(flow, AdT, G1);
    final_kernel<<<dim3(NN, 64), 256, 0, stream>>>(xtcn, G1, Wg, Wt, bg, W1, b1, W2, b2,
                                                   ncnt, nidx, nw, out);
}

// Round 6
// 292.212 us; speedup vs baseline: 1.3769x; 1.0049x over previous
//
#include <hip/hip_runtime.h>
#include <hip/hip_bf16.h>
#include <math.h>

// ---- problem constants ----
#define NB 256      // batch
#define NN 307      // vertices
#define NBN 78592   // NB*NN
#define LL 12       // sequence length
#define DDIM 16     // model dim
#define HISW 268    // 267 history cols + 1 zero pad (for float4)
#define HIS4 67     // HISW/4
#define NBRCAP 64   // per-row neighbor capacity (mean 9.2, 64 is ~18 sigma)
#define AGRP 15     // bn rows per 192-thread block in attn (180 lanes active)
#define ADTS 308    // AdT row stride (padded even for float2 alignment)

// ---- workspace layout (float offsets; every segment 16B-aligned) ----
// xtcn is now bf16 (ushort): occupies half its old region.
#define OFF_XTCN 0u            // 15089664 ushorts [B,N,L,D] bf16
#define OFF_G1   15089664u     //   943104 floats  [B,N,L]
#define OFF_ADT  16032768u     //    94688 floats  A_dyn^T [m][308]
#define OFF_TEQ  16127456u     //    49152 floats  [B,L,16]  (te@Wq+bq)/sqrt2
#define OFF_HIS  16176608u     //    82288 floats  [N,268]; TEK overlays (adyn first)
#define OFF_TEK  16176608u     //    49152 floats  te@Wk+bk   (aliases HIS)
#define OFF_NW   16258896u     //    19648 floats  nbr weights [N,64]
#define OFF_NIDX 16278544u     //    19648 ints    nbr indices [N,64]
#define OFF_NCNT 16298192u     //      320 ints    nbr counts
#define OFF_TEV  16298512u     //    49152 floats  te@Wv+bv
#define OFF_TEO  16347664u     //    49152 floats  te+bo

__device__ inline float4 mkf4(float a, float b, float c, float d) {
    float4 r; r.x = a; r.y = b; r.z = c; r.w = d; return r;
}

// ---------------------------------------------------------------------------
// K0a: build padded history matrix his[N][268]
// ---------------------------------------------------------------------------
__global__ void his_kernel(const float* __restrict__ flow, float* __restrict__ his) {
    int e = blockIdx.x * 256 + threadIdx.x;
    if (e >= NN * HISW) return;
    int n = e / HISW, j = e - n * HISW;
    float v = 0.f;
    if (j < LL) v = flow[n * LL + j];
    else if (j < 267) v = flow[((j - 11) * NN + n) * LL + 11];
    his[e] = v;
}

// ---------------------------------------------------------------------------
// K0b v2: TE tables. Row (b,l): te = pe + day_emb + week_emb, then
//   TEQ = (te@Wq+bq)/sqrt2, TEK = te@Wk+bk, TEV = te@Wv+bv, TEO = te+bo.
// ---------------------------------------------------------------------------
__global__ __launch_bounds__(256) void te_kernel(
    const int* __restrict__ dayc, const int* __restrict__ weekc,
    const float* __restrict__ demb, const float* __restrict__ wemb,
    const float* __restrict__ Wq, const float* __restrict__ bq,
    const float* __restrict__ Wk, const float* __restrict__ bk,
    const float* __restrict__ Wv, const float* __restrict__ bv,
    const float* __restrict__ bo,
    float* __restrict__ TEQ, float* __restrict__ TEK,
    float* __restrict__ TEV, float* __restrict__ TEO) {
    __shared__ float sTE[16][16];
    int t = threadIdx.x, r = t >> 4, d = t & 15;
    int row = blockIdx.x * 16 + r;            // row < NB*LL = 3072
    int b = row / LL, l = row - b * LL;
    int dc = dayc[b * LL + l], wc = weekc[b * LL + l];
    int i = d >> 1;
    float ang = (float)l * powf(10000.f, -0.125f * (float)i);
    float pe = (d & 1) ? cosf(ang) : sinf(ang);
    float te = demb[dc * DDIM + d] + wemb[wc * DDIM + d] + pe;
    sTE[r][d] = te;
    __syncthreads();
    float aq = bq[d], ak = bk[d], av = bv[d];
#pragma unroll
    for (int e = 0; e < 16; e++) {
        float x = sTE[r][e];
        aq += x * Wq[e * 16 + d];
        ak += x * Wk[e * 16 + d];
        av += x * Wv[e * 16 + d];
    }
    TEQ[row * 16 + d] = aq * 0.70710678118654752f;
    TEK[row * 16 + d] = ak;
    TEV[row * 16 + d] = av;
    TEO[row * 16 + d] = te + bo[d];
}

// ---------------------------------------------------------------------------
// K1: A_dyn row-softmax of -dist, stored transposed AdT[m*308+n]
// ---------------------------------------------------------------------------
__global__ __launch_bounds__(256) void adyn_kernel(const float* __restrict__ his,
                                                   float* __restrict__ AdT) {
    __shared__ float4 sh[HIS4];
    __shared__ float red[256];
    int n = blockIdx.x, t = threadIdx.x;
    if (t < HIS4) sh[t] = reinterpret_cast<const float4*>(his)[n * HIS4 + t];
    __syncthreads();

    float e0 = 0.f, e1 = 0.f, lsum = 0.f;
    {
        const float4* row = reinterpret_cast<const float4*>(his) + t * HIS4;
        float4 acc = mkf4(0.f, 0.f, 0.f, 0.f);
        for (int j = 0; j < HIS4; j++) {
            float4 a = sh[j], b = row[j];
            float dx = a.x - b.x, dy = a.y - b.y, dz = a.z - b.z, dw = a.w - b.w;
            acc.x += dx * dx; acc.y += dy * dy; acc.z += dz * dz; acc.w += dw * dw;
        }
        float d2 = (acc.x + acc.y) + (acc.z + acc.w);
        e0 = __expf(-sqrtf(fmaxf(d2, 0.f)));
        lsum += e0;
    }
    int m1 = t + 256;
    if (m1 < NN) {
        const float4* row = reinterpret_cast<const float4*>(his) + m1 * HIS4;
        float4 acc = mkf4(0.f, 0.f, 0.f, 0.f);
        for (int j = 0; j < HIS4; j++) {
            float4 a = sh[j], b = row[j];
            float dx = a.x - b.x, dy = a.y - b.y, dz = a.z - b.z, dw = a.w - b.w;
            acc.x += dx * dx; acc.y += dy * dy; acc.z += dz * dz; acc.w += dw * dw;
        }
        float d2 = (acc.x + acc.y) + (acc.z + acc.w);
        e1 = __expf(-sqrtf(fmaxf(d2, 0.f)));
        lsum += e1;
    }
    red[t] = lsum;
    __syncthreads();
    for (int s = 128; s > 0; s >>= 1) {
        if (t < s) red[t] += red[t + s];
        __syncthreads();
    }
    float inv = 1.f / red[0];
    AdT[t * ADTS + n] = e0 * inv;
    if (m1 < NN) AdT[m1 * ADTS + n] = e1 * inv;
}

// ---------------------------------------------------------------------------
// K2: sparse A_st rows (ballot compaction)
// ---------------------------------------------------------------------------
__global__ __launch_bounds__(64) void nbr_kernel(const float* __restrict__ adj,
                                                 int* __restrict__ ncnt,
                                                 int* __restrict__ nidx,
                                                 float* __restrict__ nw) {
    int n = blockIdx.x, t = threadIdx.x;
    float rs = 0.f;
    for (int m0 = 0; m0 < NN; m0 += 64) {
        int m = m0 + t;
        if (m < NN) rs += adj[n * NN + m];
    }
    for (int off = 32; off > 0; off >>= 1) rs += __shfl_xor(rs, off);
    float inv = 1.f / (rs + 1.f);
    int c = 0;
    for (int m0 = 0; m0 < NN; m0 += 64) {
        int m = m0 + t;
        float a = (m < NN) ? adj[n * NN + m] : 0.f;
        bool p = (a != 0.f);
        unsigned long long mask = __ballot(p);
        int pos = __popcll(mask & ((1ull << t) - 1ull));
        if (p && (c + pos) < NBRCAP) {
            nidx[n * NBRCAP + c + pos] = m;
            nw[n * NBRCAP + c + pos] = a * inv;
        }
        c += (int)__popcll(mask);
    }
    if (t == 0) ncnt[n] = c < NBRCAP ? c : NBRCAP;
}

// ---------------------------------------------------------------------------
// K3 v6: temporal self-attention (v5 structure) with bf16 xtcn output.
// ---------------------------------------------------------------------------
__global__ __launch_bounds__(192, 5) void attn_kernel(
    const float* __restrict__ flow,
    const float* __restrict__ TEQ, const float* __restrict__ TEK,
    const float* __restrict__ TEV, const float* __restrict__ TEO,
    const float* __restrict__ Wq, const float* __restrict__ Wk,
    const float* __restrict__ Wv, const float* __restrict__ Wo,
    unsigned short* __restrict__ xtcn) {
    __shared__ __align__(16) float sWo[256];
    __shared__ __align__(16) float sWs[48];   // [0..15]=wq1/sqrt2, [16..31]=wk1, [32..47]=wv1
    __shared__ __align__(16) float sKV[2][AGRP][LL][20];

    const int t = threadIdx.x;
    for (int id = t; id < 256; id += 192) sWo[id] = Wo[id];
    if (t < 48) {
        int mat = t >> 4, d = t & 15;
        const float* W = (mat == 0) ? Wq : (mat == 1) ? Wk : Wv;
        float s = 0.f;
#pragma unroll
        for (int e = 0; e < 16; e++) s += W[e * 16 + d];
        sWs[t] = (mat == 0) ? s * 0.70710678118654752f : s;
    }

    const int g = t / LL, l = t - g * LL;
    const int bn = blockIdx.x * AGRP + g;
    const bool act = (t < AGRP * LL) && (bn < NBN);

    float f = 0.f;
    float tq[16], tk[16], tv[16];
    int row = 0;
    if (act) {
        const int b = bn / NN;
        row = b * LL + l;
        f = flow[bn * LL + l];
        const float4* q4 = reinterpret_cast<const float4*>(TEQ + row * 16);
        const float4* k4 = reinterpret_cast<const float4*>(TEK + row * 16);
        const float4* v4 = reinterpret_cast<const float4*>(TEV + row * 16);
#pragma unroll
        for (int j = 0; j < 4; j++) {
            float4 a = q4[j]; tq[4 * j] = a.x; tq[4 * j + 1] = a.y; tq[4 * j + 2] = a.z; tq[4 * j + 3] = a.w;
            float4 bb = k4[j]; tk[4 * j] = bb.x; tk[4 * j + 1] = bb.y; tk[4 * j + 2] = bb.z; tk[4 * j + 3] = bb.w;
            float4 c = v4[j]; tv[4 * j] = c.x; tv[4 * j + 1] = c.y; tv[4 * j + 2] = c.z; tv[4 * j + 3] = c.w;
        }
    }
    __syncthreads();   // sWo/sWs ready

    float q[16];
    if (act) {
        float k[16], v[16];
        const float4* ws4 = reinterpret_cast<const float4*>(sWs);
#pragma unroll
        for (int j = 0; j < 4; j++) {
            float4 wq = ws4[j], wk = ws4[4 + j], wv = ws4[8 + j];
            q[4 * j] = tq[4 * j] + f * wq.x;       q[4 * j + 1] = tq[4 * j + 1] + f * wq.y;
            q[4 * j + 2] = tq[4 * j + 2] + f * wq.z; q[4 * j + 3] = tq[4 * j + 3] + f * wq.w;
            k[4 * j] = tk[4 * j] + f * wk.x;       k[4 * j + 1] = tk[4 * j + 1] + f * wk.y;
            k[4 * j + 2] = tk[4 * j + 2] + f * wk.z; k[4 * j + 3] = tk[4 * j + 3] + f * wk.w;
            v[4 * j] = tv[4 * j] + f * wv.x;       v[4 * j + 1] = tv[4 * j + 1] + f * wv.y;
            v[4 * j + 2] = tv[4 * j + 2] + f * wv.z; v[4 * j + 3] = tv[4 * j + 3] + f * wv.w;
        }
        float4* kd = reinterpret_cast<float4*>(&sKV[0][g][l][0]);
        float4* vd = reinterpret_cast<float4*>(&sKV[1][g][l][0]);
#pragma unroll
        for (int j = 0; j < 4; j++) {
            kd[j] = mkf4(k[4 * j], k[4 * j + 1], k[4 * j + 2], k[4 * j + 3]);
            vd[j] = mkf4(v[4 * j], v[4 * j + 1], v[4 * j + 2], v[4 * j + 3]);
        }
    }
    __syncthreads();   // k,v visible

    if (act) {
        float att[16];
#pragma unroll
        for (int h = 0; h < 8; h++) {
            float qx = q[2 * h], qy = q[2 * h + 1];
            float s[LL];
            float sum = 0.f;
#pragma unroll
            for (int m = 0; m < LL; m++) {
                float2 kk = *reinterpret_cast<const float2*>(&sKV[0][g][m][2 * h]);
                s[m] = __expf(qx * kk.x + qy * kk.y);   // 1/sqrt2 folded into q
                sum += s[m];
            }
            float a0 = 0.f, a1 = 0.f;
#pragma unroll
            for (int m = 0; m < LL; m++) {
                float2 vv = *reinterpret_cast<const float2*>(&sKV[1][g][m][2 * h]);
                a0 += s[m] * vv.x; a1 += s[m] * vv.y;
            }
            float inv = 1.f / sum;
            att[2 * h] = a0 * inv; att[2 * h + 1] = a1 * inv;
        }
        // o = TEO[b,l] + att@Wo; result = o + f (residual+bias folded into TEO)
        float o[16];
        const float4* to4 = reinterpret_cast<const float4*>(TEO + row * 16);
#pragma unroll
        for (int j = 0; j < 4; j++) {
            float4 a = to4[j];
            o[4 * j] = a.x; o[4 * j + 1] = a.y; o[4 * j + 2] = a.z; o[4 * j + 3] = a.w;
        }
#pragma unroll
        for (int e = 0; e < 16; e++) {
            float ae = att[e];
            const float4* wo = reinterpret_cast<const float4*>(&sWo[e * 16]);
#pragma unroll
            for (int j = 0; j < 4; j++) {
                float4 w = wo[j];
                o[4 * j] += ae * w.x; o[4 * j + 1] += ae * w.y;
                o[4 * j + 2] += ae * w.z; o[4 * j + 3] += ae * w.w;
            }
        }
        // pack to bf16 (round-half-up) and store 2x16B
        unsigned pk[8];
#pragma unroll
        for (int j = 0; j < 8; j++) {
            unsigned u0 = __float_as_uint(o[2 * j] + f) + 0x8000u;
            unsigned u1 = __float_as_uint(o[2 * j + 1] + f) + 0x8000u;
            pk[j] = (u0 >> 16) | (u1 & 0xffff0000u);
        }
        uint4* dst = reinterpret_cast<uint4*>(xtcn + (size_t)bn * 192 + l * 16);
        uint4 d0; d0.x = pk[0]; d0.y = pk[1]; d0.z = pk[2]; d0.w = pk[3];
        uint4 d1; d1.x = pk[4]; d1.y = pk[5]; d1.z = pk[6]; d1.w = pk[7];
        dst[0] = d0; dst[1] = d1;
    }
}

// ---------------------------------------------------------------------------
// K4 v3: G1[b,:,:] = A_dyn @ flow[b]. Block = (b, 128-n tile); flow[b] staged
// in LDS; AdT read coalesced as float2. No atomics.
// ---------------------------------------------------------------------------
__global__ __launch_bounds__(256) void g1_kernel(const float* __restrict__ flow,
                                                 const float* __restrict__ AdT,
                                                 float* __restrict__ G1) {
    __shared__ float sflow[NN * LL];   // 3684 floats
    int b = blockIdx.x, nt = blockIdx.y, t = threadIdx.x;
    const float* fb = flow + (size_t)b * (NN * LL);
    for (int e = t; e < NN * LL; e += 256) sflow[e] = fb[e];
    __syncthreads();

    int lane = t & 63, lq = t >> 6;
    int n = nt * 128 + 2 * lane;
    int l0 = lq * 3;
    float a00 = 0.f, a01 = 0.f, a02 = 0.f, a10 = 0.f, a11 = 0.f, a12 = 0.f;
#pragma unroll 4
    for (int m = 0; m < NN; m++) {
        float2 w = reinterpret_cast<const float2*>(AdT + (size_t)m * ADTS + nt * 128)[lane];
        float f0 = sflow[m * LL + l0];
        float f1 = sflow[m * LL + l0 + 1];
        float f2 = sflow[m * LL + l0 + 2];
        a00 += w.x * f0; a01 += w.x * f1; a02 += w.x * f2;
        a10 += w.y * f0; a11 += w.y * f1; a12 += w.y * f2;
    }
    if (n < NN) {
        float* dst = G1 + ((size_t)b * NN + n) * LL + l0;
        dst[0] = a00; dst[1] = a01; dst[2] = a02;
    }
    if (n + 1 < NN) {
        float* dst = G1 + ((size_t)b * NN + n + 1) * LL + l0;
        dst[0] = a10; dst[1] = a11; dst[2] = a12;
    }
}

// ---------------------------------------------------------------------------
// K5 v4: fused graph-mix + per-vertex MLP.
// Changes vs v3 (87.6us, FETCH 180MB, 3.77M bank conflicts):
//  - xtcn gather in bf16: lane t<48 reads one uint2 (4 bf16) per neighbor
//    (1 load vs 3, half the bytes), unpack+FMA into 4 register accumulators.
//  - sY row stride 16->20 floats: hid-stage float4 reads conflict-free.
//  - sHID row stride 8->10 float4s (40 floats): h1-stage reads 2-way (free),
//    writes uniform 8 words/bank (optimal).
// ---------------------------------------------------------------------------
__global__ __launch_bounds__(256) void final_kernel(
    const unsigned short* __restrict__ xtcn, const float* __restrict__ G1,
    const float* __restrict__ Wg, const float* __restrict__ Wt,
    const float* __restrict__ bg, const float* __restrict__ W1,
    const float* __restrict__ b1, const float* __restrict__ W2,
    const float* __restrict__ b2, const int* __restrict__ ncnt,
    const int* __restrict__ nidx, const float* __restrict__ nw,
    float* __restrict__ out) {
    __shared__ __align__(16) float sWt[512];
    __shared__ __align__(16) float sW1[256];
    __shared__ __align__(16) float sWg[32];
    __shared__ __align__(16) float sBg[32];
    __shared__ float sB1[8], sW2[8];
    __shared__ __align__(16) float sY[4][240];      // stride 20 per l
    __shared__ __align__(16) float4 sHID[4][120];   // stride 10 float4 per l
    __shared__ float sH1[4][96];

    int t = threadIdx.x;
    int n = blockIdx.x;
    int w = t >> 6, t64 = t & 63;
    int b = blockIdx.y * 4 + w;

    // stage weights
    sW1[t] = W1[n * 256 + t];
    sWt[t] = Wt[t];
    sWt[t + 256] = Wt[t + 256];
    if (t < 32) sWg[t] = Wg[t];
    else if (t < 64) sBg[t - 32] = bg[t - 32];
    else if (t < 72) sB1[t - 64] = b1[n * 8 + (t - 64)];
    else if (t < 80) sW2[t - 72] = W2[n * 8 + (t - 72)];
    float b2v = b2[n];
    int cnt = ncnt[n];
    __syncthreads();

    // sparse gather (bf16): lane t64<48 owns elements 4*t64 .. 4*t64+3
    if (t64 < 48) {
        float y0 = 0.f, y1 = 0.f, y2 = 0.f, y3 = 0.f;
        const unsigned short* base = xtcn + (size_t)b * NN * 192;
        int i = 0;
        for (; i + 1 < cnt; i += 2) {
            int ma = nidx[n * NBRCAP + i], mb = nidx[n * NBRCAP + i + 1];
            float wa = nw[n * NBRCAP + i], wb = nw[n * NBRCAP + i + 1];
            uint2 pa = reinterpret_cast<const uint2*>(base + ma * 192)[t64];
            uint2 pb = reinterpret_cast<const uint2*>(base + mb * 192)[t64];
            y0 += wa * __uint_as_float(pa.x << 16) + wb * __uint_as_float(pb.x << 16);
            y1 += wa * __uint_as_float(pa.x & 0xffff0000u) + wb * __uint_as_float(pb.x & 0xffff0000u);
            y2 += wa * __uint_as_float(pa.y << 16) + wb * __uint_as_float(pb.y << 16);
            y3 += wa * __uint_as_float(pa.y & 0xffff0000u) + wb * __uint_as_float(pb.y & 0xffff0000u);
        }
        if (i < cnt) {
            int ma = nidx[n * NBRCAP + i];
            float wa = nw[n * NBRCAP + i];
            uint2 pa = reinterpret_cast<const uint2*>(base + ma * 192)[t64];
            y0 += wa * __uint_as_float(pa.x << 16);
            y1 += wa * __uint_as_float(pa.x & 0xffff0000u);
            y2 += wa * __uint_as_float(pa.y << 16);
            y3 += wa * __uint_as_float(pa.y & 0xffff0000u);
        }
        int l = t64 >> 2, p = (t64 & 3);           // element 4t: l = 4t/16, pos = 4t%16
        reinterpret_cast<float4*>(&sY[w][l * 20])[p] = mkf4(y0, y1, y2, y3);
    }
    __syncthreads();

    // hid = relu(G1*Wg + y@Wt + bg)  -> sHID[w], stride 10 float4 per l
#pragma unroll
    for (int p = 0; p < 2; p++) {
        int c = t64 + p * 64;
        if (c < 96) {
            int l = c >> 3, j = c & 7;
            float g = G1[((size_t)b * NN + n) * LL + l];
            float4 wg = reinterpret_cast<const float4*>(sWg)[j];
            float4 acc = reinterpret_cast<const float4*>(sBg)[j];
            acc.x += g * wg.x; acc.y += g * wg.y; acc.z += g * wg.z; acc.w += g * wg.w;
            const float4* yr = reinterpret_cast<const float4*>(&sY[w][l * 20]);
            float4 v0 = yr[0], v1 = yr[1], v2 = yr[2], v3 = yr[3];
            float ye[16] = {v0.x, v0.y, v0.z, v0.w, v1.x, v1.y, v1.z, v1.w,
                            v2.x, v2.y, v2.z, v2.w, v3.x, v3.y, v3.z, v3.w};
#pragma unroll
            for (int d = 0; d < 16; d++) {
                float4 wt = reinterpret_cast<const float4*>(sWt)[d * 8 + j];
                acc.x += ye[d] * wt.x; acc.y += ye[d] * wt.y;
                acc.z += ye[d] * wt.z; acc.w += ye[d] * wt.w;
            }
            acc.x = fmaxf(acc.x, 0.f); acc.y = fmaxf(acc.y, 0.f);
            acc.z = fmaxf(acc.z, 0.f); acc.w = fmaxf(acc.w, 0.f);
            sHID[w][l * 10 + j] = acc;
        }
    }
    __syncthreads();

    // h1 = relu(hid @ W1[n] + b1[n])
#pragma unroll
    for (int p = 0; p < 2; p++) {
        int o = t64 + p * 64;
        if (o < 96) {
            int l = o >> 3, oo = o & 7;
            float acc = sB1[oo];
            float he[32];
#pragma unroll
            for (int k = 0; k < 8; k++) {
                float4 hv = sHID[w][l * 10 + k];
                he[4 * k + 0] = hv.x; he[4 * k + 1] = hv.y;
                he[4 * k + 2] = hv.z; he[4 * k + 3] = hv.w;
            }
#pragma unroll
            for (int c = 0; c < 32; c++) acc += he[c] * sW1[c * 8 + oo];
            sH1[w][o] = fmaxf(acc, 0.f);
        }
    }
    __syncthreads();

    // out = h1 @ W2[n] + b2[n]
    if (t64 < LL) {
        float acc = b2v;
#pragma unroll
        for (int o = 0; o < 8; o++) acc += sH1[w][t64 * 8 + o] * sW2[o];
        out[((size_t)b * NN + n) * LL + t64] = acc;
    }
}

// ---------------------------------------------------------------------------
extern "C" void kernel_launch(void* const* d_in, const int* in_sizes, int n_in,
                              void* d_out, int out_size, void* d_ws, size_t ws_size,
                              hipStream_t stream) {
    const float* flow = (const float*)d_in[0];
    const int* dayc   = (const int*)d_in[1];
    const int* weekc  = (const int*)d_in[2];
    const float* adj  = (const float*)d_in[3];
    const float* demb = (const float*)d_in[4];
    const float* wemb = (const float*)d_in[5];
    const float* Wq = (const float*)d_in[6];  const float* bq = (const float*)d_in[7];
    const float* Wk = (const float*)d_in[8];  const float* bk = (const float*)d_in[9];
    const float* Wv = (const float*)d_in[10]; const float* bv = (const float*)d_in[11];
    const float* Wo = (const float*)d_in[12]; const float* bo = (const float*)d_in[13];
    const float* Wg = (const float*)d_in[14]; const float* Wt = (const float*)d_in[15];
    const float* bg = (const float*)d_in[16];
    const float* W1 = (const float*)d_in[17]; const float* b1 = (const float*)d_in[18];
    const float* W2 = (const float*)d_in[19]; const float* b2 = (const float*)d_in[20];
    float* out = (float*)d_out;
    float* ws  = (float*)d_ws;

    unsigned short* xtcn = (unsigned short*)(ws + 0);   // bf16 region
    float* G1   = ws + OFF_G1;
    float* AdT  = ws + OFF_ADT;
    float* TEQ  = ws + OFF_TEQ;
    float* TEK  = ws + OFF_TEK;   // overlays his (adyn runs first)
    float* TEV  = ws + OFF_TEV;
    float* TEO  = ws + OFF_TEO;
    float* his  = ws + OFF_HIS;
    float* nw   = ws + OFF_NW;
    int*   nidx = (int*)(ws + OFF_NIDX);
    int*   ncnt = (int*)(ws + OFF_NCNT);

    // his -> adyn first (TEK overlays the his buffer afterwards)
    his_kernel<<<(NN * HISW + 255) / 256, 256, 0, stream>>>(flow, his);
    adyn_kernel<<<NN, 256, 0, stream>>>(his, AdT);
    te_kernel<<<(NB * LL) / 16, 256, 0, stream>>>(dayc, weekc, demb, wemb,
                                                  Wq, bq, Wk, bk, Wv, bv, bo,
                                                  TEQ, TEK, TEV, TEO);
    nbr_kernel<<<NN, 64, 0, stream>>>(adj, ncnt, nidx, nw);
    attn_kernel<<<(NBN + AGRP - 1) / AGRP, 192, 0, stream>>>(flow, TEQ, TEK, TEV, TEO,
                                                             Wq, Wk, Wv, Wo, xtcn);
    g1_kernel<<<dim3(NB, 3), 256, 0, stream>>>(flow, AdT, G1);
    final_kernel<<<dim3(NN, 64), 256, 0, stream>>>(xtcn, G1, Wg, Wt, bg, W1, b1, W2, b2,
                                                   ncnt, nidx, nw, out);
}

// Round 7
// 284.636 us; speedup vs baseline: 1.4136x; 1.0266x over previous
//
#include <hip/hip_runtime.h>
#include <hip/hip_bf16.h>
#include <math.h>

// ---- problem constants ----
#define NB 256      // batch
#define NN 307      // vertices
#define NBN 78592   // NB*NN
#define LL 12       // sequence length
#define DDIM 16     // model dim
#define HISW 268    // 267 history cols + 1 zero pad (for float4)
#define HIS4 67     // HISW/4
#define NBRCAP 64   // per-row neighbor capacity (mean 9.2, 64 is ~18 sigma)
#define AGRP 15     // bn rows per 192-thread block in attn
#define ADTS 308    // AdT row stride (padded even for float2 alignment)

// ---- workspace layout (float offsets; every segment 16B-aligned) ----
#define OFF_XTCN 0u            // 15089664 ushorts [B,N,L,D] bf16
#define OFF_G1   15089664u     //   943104 floats  [B,N,L]
#define OFF_ADT  16032768u     //    94688 floats  A_dyn^T [m][308]
#define OFF_TEQ  16127456u     //    49152 floats  [B,L,16]  (te@Wq+bq)/sqrt2
#define OFF_HIS  16176608u     //    82288 floats  [N,268]; TEK overlays (adyn first)
#define OFF_TEK  16176608u     //    49152 floats  te@Wk+bk   (aliases HIS)
#define OFF_NW   16258896u     //    19648 floats  nbr weights [N,64]
#define OFF_NIDX 16278544u     //    19648 ints    nbr indices [N,64]
#define OFF_NCNT 16298192u     //      320 ints    nbr counts
#define OFF_TEV  16298512u     //    49152 floats  te@Wv+bv
#define OFF_TEO  16347664u     //    49152 floats  te+bo

__device__ inline float4 mkf4(float a, float b, float c, float d) {
    float4 r; r.x = a; r.y = b; r.z = c; r.w = d; return r;
}

// ---------------------------------------------------------------------------
// K0a: build padded history matrix his[N][268]
// ---------------------------------------------------------------------------
__global__ void his_kernel(const float* __restrict__ flow, float* __restrict__ his) {
    int e = blockIdx.x * 256 + threadIdx.x;
    if (e >= NN * HISW) return;
    int n = e / HISW, j = e - n * HISW;
    float v = 0.f;
    if (j < LL) v = flow[n * LL + j];
    else if (j < 267) v = flow[((j - 11) * NN + n) * LL + 11];
    his[e] = v;
}

// ---------------------------------------------------------------------------
// K0b v2: TE tables. Row (b,l): te = pe + day_emb + week_emb, then
//   TEQ = (te@Wq+bq)/sqrt2, TEK = te@Wk+bk, TEV = te@Wv+bv, TEO = te+bo.
// ---------------------------------------------------------------------------
__global__ __launch_bounds__(256) void te_kernel(
    const int* __restrict__ dayc, const int* __restrict__ weekc,
    const float* __restrict__ demb, const float* __restrict__ wemb,
    const float* __restrict__ Wq, const float* __restrict__ bq,
    const float* __restrict__ Wk, const float* __restrict__ bk,
    const float* __restrict__ Wv, const float* __restrict__ bv,
    const float* __restrict__ bo,
    float* __restrict__ TEQ, float* __restrict__ TEK,
    float* __restrict__ TEV, float* __restrict__ TEO) {
    __shared__ float sTE[16][16];
    int t = threadIdx.x, r = t >> 4, d = t & 15;
    int row = blockIdx.x * 16 + r;            // row < NB*LL = 3072
    int b = row / LL, l = row - b * LL;
    int dc = dayc[b * LL + l], wc = weekc[b * LL + l];
    int i = d >> 1;
    float ang = (float)l * powf(10000.f, -0.125f * (float)i);
    float pe = (d & 1) ? cosf(ang) : sinf(ang);
    float te = demb[dc * DDIM + d] + wemb[wc * DDIM + d] + pe;
    sTE[r][d] = te;
    __syncthreads();
    float aq = bq[d], ak = bk[d], av = bv[d];
#pragma unroll
    for (int e = 0; e < 16; e++) {
        float x = sTE[r][e];
        aq += x * Wq[e * 16 + d];
        ak += x * Wk[e * 16 + d];
        av += x * Wv[e * 16 + d];
    }
    TEQ[row * 16 + d] = aq * 0.70710678118654752f;
    TEK[row * 16 + d] = ak;
    TEV[row * 16 + d] = av;
    TEO[row * 16 + d] = te + bo[d];
}

// ---------------------------------------------------------------------------
// K1: A_dyn row-softmax of -dist, stored transposed AdT[m*308+n]
// ---------------------------------------------------------------------------
__global__ __launch_bounds__(256) void adyn_kernel(const float* __restrict__ his,
                                                   float* __restrict__ AdT) {
    __shared__ float4 sh[HIS4];
    __shared__ float red[256];
    int n = blockIdx.x, t = threadIdx.x;
    if (t < HIS4) sh[t] = reinterpret_cast<const float4*>(his)[n * HIS4 + t];
    __syncthreads();

    float e0 = 0.f, e1 = 0.f, lsum = 0.f;
    {
        const float4* row = reinterpret_cast<const float4*>(his) + t * HIS4;
        float4 acc = mkf4(0.f, 0.f, 0.f, 0.f);
        for (int j = 0; j < HIS4; j++) {
            float4 a = sh[j], b = row[j];
            float dx = a.x - b.x, dy = a.y - b.y, dz = a.z - b.z, dw = a.w - b.w;
            acc.x += dx * dx; acc.y += dy * dy; acc.z += dz * dz; acc.w += dw * dw;
        }
        float d2 = (acc.x + acc.y) + (acc.z + acc.w);
        e0 = __expf(-sqrtf(fmaxf(d2, 0.f)));
        lsum += e0;
    }
    int m1 = t + 256;
    if (m1 < NN) {
        const float4* row = reinterpret_cast<const float4*>(his) + m1 * HIS4;
        float4 acc = mkf4(0.f, 0.f, 0.f, 0.f);
        for (int j = 0; j < HIS4; j++) {
            float4 a = sh[j], b = row[j];
            float dx = a.x - b.x, dy = a.y - b.y, dz = a.z - b.z, dw = a.w - b.w;
            acc.x += dx * dx; acc.y += dy * dy; acc.z += dz * dz; acc.w += dw * dw;
        }
        float d2 = (acc.x + acc.y) + (acc.z + acc.w);
        e1 = __expf(-sqrtf(fmaxf(d2, 0.f)));
        lsum += e1;
    }
    red[t] = lsum;
    __syncthreads();
    for (int s = 128; s > 0; s >>= 1) {
        if (t < s) red[t] += red[t + s];
        __syncthreads();
    }
    float inv = 1.f / red[0];
    AdT[t * ADTS + n] = e0 * inv;
    if (m1 < NN) AdT[m1 * ADTS + n] = e1 * inv;
}

// ---------------------------------------------------------------------------
// K2: sparse A_st rows (ballot compaction)
// ---------------------------------------------------------------------------
__global__ __launch_bounds__(64) void nbr_kernel(const float* __restrict__ adj,
                                                 int* __restrict__ ncnt,
                                                 int* __restrict__ nidx,
                                                 float* __restrict__ nw) {
    int n = blockIdx.x, t = threadIdx.x;
    float rs = 0.f;
    for (int m0 = 0; m0 < NN; m0 += 64) {
        int m = m0 + t;
        if (m < NN) rs += adj[n * NN + m];
    }
    for (int off = 32; off > 0; off >>= 1) rs += __shfl_xor(rs, off);
    float inv = 1.f / (rs + 1.f);
    int c = 0;
    for (int m0 = 0; m0 < NN; m0 += 64) {
        int m = m0 + t;
        float a = (m < NN) ? adj[n * NN + m] : 0.f;
        bool p = (a != 0.f);
        unsigned long long mask = __ballot(p);
        int pos = __popcll(mask & ((1ull << t) - 1ull));
        if (p && (c + pos) < NBRCAP) {
            nidx[n * NBRCAP + c + pos] = m;
            nw[n * NBRCAP + c + pos] = a * inv;
        }
        c += (int)__popcll(mask);
    }
    if (t == 0) ncnt[n] = c < NBRCAP ? c : NBRCAP;
}

// ---------------------------------------------------------------------------
// K3 v7: temporal self-attention, head-lane formulation.
// After the TE-table algebra, q/k/v construction is 6 FMA per (l,head-pair)
// regardless of which lane does it -> fold it into the softmax stage:
//   lane (g,h) (120 of 192): loads flow row (3xb128) + TEQ/TEK/TEV pairs
//   (36 b64, L2-hot), builds q/k/v pairs in regs, does 12 softmax rows,
//   writes att pairs to sA[g][l][2h] (self-owned slots -> race-free).
//   lane (g,l) (180 of 192) after barrier: att@Wo + TEO + flow -> bf16 store.
// No K/V/Q LDS: LDS 28.5->16KB, LDS instr/lane 192->~30.
// ---------------------------------------------------------------------------
__global__ __launch_bounds__(192) void attn_kernel(
    const float* __restrict__ flow,
    const float* __restrict__ TEQ, const float* __restrict__ TEK,
    const float* __restrict__ TEV, const float* __restrict__ TEO,
    const float* __restrict__ Wq, const float* __restrict__ Wk,
    const float* __restrict__ Wv, const float* __restrict__ Wo,
    unsigned short* __restrict__ xtcn) {
    __shared__ __align__(16) float sWo[256];
    __shared__ __align__(16) float sWs[48];   // [0..15]=wq1/sqrt2, [16..31]=wk1, [32..47]=wv1
    __shared__ __align__(16) float sA[AGRP][LL][20];

    const int t = threadIdx.x;
    for (int id = t; id < 256; id += 192) sWo[id] = Wo[id];
    if (t < 48) {
        int mat = t >> 4, d = t & 15;
        const float* W = (mat == 0) ? Wq : (mat == 1) ? Wk : Wv;
        float s = 0.f;
#pragma unroll
        for (int e = 0; e < 16; e++) s += W[e * 16 + d];
        sWs[t] = (mat == 0) ? s * 0.70710678118654752f : s;
    }
    __syncthreads();

    // ---- stage B: lanes (g,h) ----
    if (t < AGRP * 8) {
        int g = t >> 3, h = t & 7;
        int bn = blockIdx.x * AGRP + g;
        if (bn < NBN) {
            int b = bn / NN;
            // flow row (12 contiguous floats, 16B-aligned)
            float f[12];
            {
                const float4* fr = reinterpret_cast<const float4*>(flow + bn * LL);
                float4 f0 = fr[0], f1 = fr[1], f2 = fr[2];
                f[0] = f0.x; f[1] = f0.y; f[2] = f0.z; f[3] = f0.w;
                f[4] = f1.x; f[5] = f1.y; f[6] = f1.z; f[7] = f1.w;
                f[8] = f2.x; f[9] = f2.y; f[10] = f2.z; f[11] = f2.w;
            }
            float wqx = sWs[2 * h], wqy = sWs[2 * h + 1];
            float wkx = sWs[16 + 2 * h], wky = sWs[16 + 2 * h + 1];
            float wvx = sWs[32 + 2 * h], wvy = sWs[32 + 2 * h + 1];
            // k,v pairs for all 12 positions (L2-hot table reads)
            const float* tekb = TEK + (b * LL) * 16 + 2 * h;
            const float* tevb = TEV + (b * LL) * 16 + 2 * h;
            const float* teqb = TEQ + (b * LL) * 16 + 2 * h;
            float kx[12], ky[12], vx[12], vy[12];
#pragma unroll
            for (int m = 0; m < LL; m++) {
                float2 tk = *reinterpret_cast<const float2*>(tekb + m * 16);
                float2 tv = *reinterpret_cast<const float2*>(tevb + m * 16);
                kx[m] = tk.x + f[m] * wkx; ky[m] = tk.y + f[m] * wky;
                vx[m] = tv.x + f[m] * wvx; vy[m] = tv.y + f[m] * wvy;
            }
#pragma unroll
            for (int l = 0; l < LL; l++) {
                float2 tq = *reinterpret_cast<const float2*>(teqb + l * 16);
                float qx = tq.x + f[l] * wqx, qy = tq.y + f[l] * wqy;
                float s[12];
                float sum = 0.f;
#pragma unroll
                for (int m = 0; m < LL; m++) {
                    s[m] = __expf(qx * kx[m] + qy * ky[m]);  // 1/sqrt2 folded into q
                    sum += s[m];
                }
                float a0 = 0.f, a1 = 0.f;
#pragma unroll
                for (int m = 0; m < LL; m++) { a0 += s[m] * vx[m]; a1 += s[m] * vy[m]; }
                float inv = 1.f / sum;
                float2 r; r.x = a0 * inv; r.y = a1 * inv;
                *reinterpret_cast<float2*>(&sA[g][l][2 * h]) = r;
            }
        }
    }
    __syncthreads();

    // ---- stage C: lanes (g,l) ----
    if (t < AGRP * LL) {
        int g = t / LL, l = t - g * LL;
        int bn = blockIdx.x * AGRP + g;
        if (bn < NBN) {
            int b = bn / NN;
            int row = b * LL + l;
            float f = flow[bn * LL + l];
            float att[16];
            const float4* ar = reinterpret_cast<const float4*>(&sA[g][l][0]);
            float4 a0 = ar[0], a1 = ar[1], a2 = ar[2], a3 = ar[3];
            att[0] = a0.x; att[1] = a0.y; att[2] = a0.z; att[3] = a0.w;
            att[4] = a1.x; att[5] = a1.y; att[6] = a1.z; att[7] = a1.w;
            att[8] = a2.x; att[9] = a2.y; att[10] = a2.z; att[11] = a2.w;
            att[12] = a3.x; att[13] = a3.y; att[14] = a3.z; att[15] = a3.w;
            float o[16];
            const float4* to4 = reinterpret_cast<const float4*>(TEO + row * 16);
#pragma unroll
            for (int j = 0; j < 4; j++) {
                float4 a = to4[j];
                o[4 * j] = a.x; o[4 * j + 1] = a.y; o[4 * j + 2] = a.z; o[4 * j + 3] = a.w;
            }
#pragma unroll
            for (int e = 0; e < 16; e++) {
                float ae = att[e];
                const float4* wo = reinterpret_cast<const float4*>(&sWo[e * 16]);
#pragma unroll
                for (int j = 0; j < 4; j++) {
                    float4 w = wo[j];
                    o[4 * j] += ae * w.x; o[4 * j + 1] += ae * w.y;
                    o[4 * j + 2] += ae * w.z; o[4 * j + 3] += ae * w.w;
                }
            }
            unsigned pk[8];
#pragma unroll
            for (int j = 0; j < 8; j++) {
                unsigned u0 = __float_as_uint(o[2 * j] + f) + 0x8000u;
                unsigned u1 = __float_as_uint(o[2 * j + 1] + f) + 0x8000u;
                pk[j] = (u0 >> 16) | (u1 & 0xffff0000u);
            }
            uint4* dst = reinterpret_cast<uint4*>(xtcn + (size_t)bn * 192 + l * 16);
            uint4 d0; d0.x = pk[0]; d0.y = pk[1]; d0.z = pk[2]; d0.w = pk[3];
            uint4 d1; d1.x = pk[4]; d1.y = pk[5]; d1.z = pk[6]; d1.w = pk[7];
            dst[0] = d0; dst[1] = d1;
        }
    }
}

// ---------------------------------------------------------------------------
// K4 v4: G1 = A_dyn @ flow[b], 2 batches per block (halves AdT L2 re-reads).
// flow addresses are wave-uniform -> readfirstlane makes them s_loads on the
// scalar pipe (no LDS, no VALU address math). AdT read coalesced float2.
// ---------------------------------------------------------------------------
__global__ __launch_bounds__(256) void g1_kernel(const float* __restrict__ flow,
                                                 const float* __restrict__ AdT,
                                                 float* __restrict__ G1) {
    int bp = blockIdx.x, nt = blockIdx.y, t = threadIdx.x;
    int lane = t & 63;
    int l0 = (t >> 6) * 3;
    int l0u = __builtin_amdgcn_readfirstlane(l0);   // wave-uniform by construction
    int n = nt * 128 + 2 * lane;
    int b0 = 2 * bp;
    const float* fb0 = flow + (size_t)b0 * (NN * LL);
    const float* fb1 = fb0 + NN * LL;

    float a000 = 0.f, a001 = 0.f, a002 = 0.f;   // [b0][n]
    float a010 = 0.f, a011 = 0.f, a012 = 0.f;   // [b0][n+1]
    float a100 = 0.f, a101 = 0.f, a102 = 0.f;   // [b0+1][n]
    float a110 = 0.f, a111 = 0.f, a112 = 0.f;   // [b0+1][n+1]
#pragma unroll 4
    for (int m = 0; m < NN; m++) {
        float2 w = reinterpret_cast<const float2*>(AdT + (size_t)m * ADTS + nt * 128)[lane];
        const float* r0 = fb0 + m * LL + l0u;
        const float* r1 = fb1 + m * LL + l0u;
        float p0 = r0[0], p1 = r0[1], p2 = r0[2];       // s_loads
        float q0 = r1[0], q1 = r1[1], q2 = r1[2];
        a000 += w.x * p0; a001 += w.x * p1; a002 += w.x * p2;
        a010 += w.y * p0; a011 += w.y * p1; a012 += w.y * p2;
        a100 += w.x * q0; a101 += w.x * q1; a102 += w.x * q2;
        a110 += w.y * q0; a111 += w.y * q1; a112 += w.y * q2;
    }
    if (n < NN) {
        float* d0 = G1 + ((size_t)b0 * NN + n) * LL + l0;
        d0[0] = a000; d0[1] = a001; d0[2] = a002;
        float* d1 = G1 + ((size_t)(b0 + 1) * NN + n) * LL + l0;
        d1[0] = a100; d1[1] = a101; d1[2] = a102;
    }
    if (n + 1 < NN) {
        float* d0 = G1 + ((size_t)b0 * NN + n + 1) * LL + l0;
        d0[0] = a010; d0[1] = a011; d0[2] = a012;
        float* d1 = G1 + ((size_t)(b0 + 1) * NN + n + 1) * LL + l0;
        d1[0] = a110; d1[1] = a111; d1[2] = a112;
    }
}

// ---------------------------------------------------------------------------
// K5 v5: fused graph-mix + per-vertex MLP. Same as v4 but hid/h1 job spaces
// (384 jobs each) are spread over all 256 lanes (1.5 full passes) instead of
// 2x 96-of-64 per-wave passes (25% idle slots).
// ---------------------------------------------------------------------------
__global__ __launch_bounds__(256) void final_kernel(
    const unsigned short* __restrict__ xtcn, const float* __restrict__ G1,
    const float* __restrict__ Wg, const float* __restrict__ Wt,
    const float* __restrict__ bg, const float* __restrict__ W1,
    const float* __restrict__ b1, const float* __restrict__ W2,
    const float* __restrict__ b2, const int* __restrict__ ncnt,
    const int* __restrict__ nidx, const float* __restrict__ nw,
    float* __restrict__ out) {
    __shared__ __align__(16) float sWt[512];
    __shared__ __align__(16) float sW1[256];
    __shared__ __align__(16) float sWg[32];
    __shared__ __align__(16) float sBg[32];
    __shared__ float sB1[8], sW2[8];
    __shared__ __align__(16) float sY[4][240];      // stride 20 per l
    __shared__ __align__(16) float4 sHID[4][120];   // stride 10 float4 per l
    __shared__ float sH1[4][96];

    int t = threadIdx.x;
    int n = blockIdx.x;
    int w = t >> 6, t64 = t & 63;
    int b = blockIdx.y * 4 + w;

    // stage weights
    sW1[t] = W1[n * 256 + t];
    sWt[t] = Wt[t];
    sWt[t + 256] = Wt[t + 256];
    if (t < 32) sWg[t] = Wg[t];
    else if (t < 64) sBg[t - 32] = bg[t - 32];
    else if (t < 72) sB1[t - 64] = b1[n * 8 + (t - 64)];
    else if (t < 80) sW2[t - 72] = W2[n * 8 + (t - 72)];
    float vb2 = b2[n];
    int cnt = ncnt[n];
    __syncthreads();

    // sparse gather (bf16): lane t64<48 owns elements 4*t64 .. 4*t64+3 of its wave's b
    if (t64 < 48) {
        float y0 = 0.f, y1 = 0.f, y2 = 0.f, y3 = 0.f;
        const unsigned short* base = xtcn + (size_t)b * NN * 192;
        int i = 0;
        for (; i + 1 < cnt; i += 2) {
            int ma = nidx[n * NBRCAP + i], mb = nidx[n * NBRCAP + i + 1];
            float wa = nw[n * NBRCAP + i], wb = nw[n * NBRCAP + i + 1];
            uint2 pa = reinterpret_cast<const uint2*>(base + ma * 192)[t64];
            uint2 pb = reinterpret_cast<const uint2*>(base + mb * 192)[t64];
            y0 += wa * __uint_as_float(pa.x << 16) + wb * __uint_as_float(pb.x << 16);
            y1 += wa * __uint_as_float(pa.x & 0xffff0000u) + wb * __uint_as_float(pb.x & 0xffff0000u);
            y2 += wa * __uint_as_float(pa.y << 16) + wb * __uint_as_float(pb.y << 16);
            y3 += wa * __uint_as_float(pa.y & 0xffff0000u) + wb * __uint_as_float(pb.y & 0xffff0000u);
        }
        if (i < cnt) {
            int ma = nidx[n * NBRCAP + i];
            float wa = nw[n * NBRCAP + i];
            uint2 pa = reinterpret_cast<const uint2*>(base + ma * 192)[t64];
            y0 += wa * __uint_as_float(pa.x << 16);
            y1 += wa * __uint_as_float(pa.x & 0xffff0000u);
            y2 += wa * __uint_as_float(pa.y << 16);
            y3 += wa * __uint_as_float(pa.y & 0xffff0000u);
        }
        int l = t64 >> 2, p = (t64 & 3);
        reinterpret_cast<float4*>(&sY[w][l * 20])[p] = mkf4(y0, y1, y2, y3);
    }
    __syncthreads();

    // hid = relu(G1*Wg + y@Wt + bg): 384 jobs over 256 lanes
#pragma unroll
    for (int p = 0; p < 2; p++) {
        int jb = t + p * 256;
        if (jb < 384) {
            int w2 = jb / 96, c = jb - w2 * 96;
            int b2i = blockIdx.y * 4 + w2;
            int l = c >> 3, j = c & 7;
            float g = G1[((size_t)b2i * NN + n) * LL + l];
            float4 wg = reinterpret_cast<const float4*>(sWg)[j];
            float4 acc = reinterpret_cast<const float4*>(sBg)[j];
            acc.x += g * wg.x; acc.y += g * wg.y; acc.z += g * wg.z; acc.w += g * wg.w;
            const float4* yr = reinterpret_cast<const float4*>(&sY[w2][l * 20]);
            float4 v0 = yr[0], v1 = yr[1], v2 = yr[2], v3 = yr[3];
            float ye[16] = {v0.x, v0.y, v0.z, v0.w, v1.x, v1.y, v1.z, v1.w,
                            v2.x, v2.y, v2.z, v2.w, v3.x, v3.y, v3.z, v3.w};
#pragma unroll
            for (int d = 0; d < 16; d++) {
                float4 wt = reinterpret_cast<const float4*>(sWt)[d * 8 + j];
                acc.x += ye[d] * wt.x; acc.y += ye[d] * wt.y;
                acc.z += ye[d] * wt.z; acc.w += ye[d] * wt.w;
            }
            acc.x = fmaxf(acc.x, 0.f); acc.y = fmaxf(acc.y, 0.f);
            acc.z = fmaxf(acc.z, 0.f); acc.w = fmaxf(acc.w, 0.f);
            sHID[w2][l * 10 + j] = acc;
        }
    }
    __syncthreads();

    // h1 = relu(hid @ W1[n] + b1[n]): 384 jobs over 256 lanes
#pragma unroll
    for (int p = 0; p < 2; p++) {
        int jb = t + p * 256;
        if (jb < 384) {
            int w2 = jb / 96, o = jb - w2 * 96;
            int l = o >> 3, oo = o & 7;
            float acc = sB1[oo];
            float he[32];
#pragma unroll
            for (int k = 0; k < 8; k++) {
                float4 hv = sHID[w2][l * 10 + k];
                he[4 * k + 0] = hv.x; he[4 * k + 1] = hv.y;
                he[4 * k + 2] = hv.z; he[4 * k + 3] = hv.w;
            }
#pragma unroll
            for (int c = 0; c < 32; c++) acc += he[c] * sW1[c * 8 + oo];
            sH1[w2][o] = fmaxf(acc, 0.f);
        }
    }
    __syncthreads();

    // out = h1 @ W2[n] + b2[n]: 48 jobs
    if (t < 48) {
        int w2 = t / 12, l = t - w2 * 12;
        int b2i = blockIdx.y * 4 + w2;
        float acc = vb2;
#pragma unroll
        for (int o = 0; o < 8; o++) acc += sH1[w2][l * 8 + o] * sW2[o];
        out[((size_t)b2i * NN + n) * LL + l] = acc;
    }
}

// ---------------------------------------------------------------------------
extern "C" void kernel_launch(void* const* d_in, const int* in_sizes, int n_in,
                              void* d_out, int out_size, void* d_ws, size_t ws_size,
                              hipStream_t stream) {
    const float* flow = (const float*)d_in[0];
    const int* dayc   = (const int*)d_in[1];
    const int* weekc  = (const int*)d_in[2];
    const float* adj  = (const float*)d_in[3];
    const float* demb = (const float*)d_in[4];
    const float* wemb = (const float*)d_in[5];
    const float* Wq = (const float*)d_in[6];  const float* bq = (const float*)d_in[7];
    const float* Wk = (const float*)d_in[8];  const float* bk = (const float*)d_in[9];
    const float* Wv = (const float*)d_in[10]; const float* bv = (const float*)d_in[11];
    const float* Wo = (const float*)d_in[12]; const float* bo = (const float*)d_in[13];
    const float* Wg = (const float*)d_in[14]; const float* Wt = (const float*)d_in[15];
    const float* bg = (const float*)d_in[16];
    const float* W1 = (const float*)d_in[17]; const float* b1 = (const float*)d_in[18];
    const float* W2 = (const float*)d_in[19]; const float* b2 = (const float*)d_in[20];
    float* out = (float*)d_out;
    float* ws  = (float*)d_ws;

    unsigned short* xtcn = (unsigned short*)(ws + 0);   // bf16 region
    float* G1   = ws + OFF_G1;
    float* AdT  = ws + OFF_ADT;
    float* TEQ  = ws + OFF_TEQ;
    float* TEK  = ws + OFF_TEK;   // overlays his (adyn runs first)
    float* TEV  = ws + OFF_TEV;
    float* TEO  = ws + OFF_TEO;
    float* his  = ws + OFF_HIS;
    float* nw   = ws + OFF_NW;
    int*   nidx = (int*)(ws + OFF_NIDX);
    int*   ncnt = (int*)(ws + OFF_NCNT);

    // his -> adyn first (TEK overlays the his buffer afterwards)
    his_kernel<<<(NN * HISW + 255) / 256, 256, 0, stream>>>(flow, his);
    adyn_kernel<<<NN, 256, 0, stream>>>(his, AdT);
    te_kernel<<<(NB * LL) / 16, 256, 0, stream>>>(dayc, weekc, demb, wemb,
                                                  Wq, bq, Wk, bk, Wv, bv, bo,
                                                  TEQ, TEK, TEV, TEO);
    nbr_kernel<<<NN, 64, 0, stream>>>(adj, ncnt, nidx, nw);
    attn_kernel<<<(NBN + AGRP - 1) / AGRP, 192, 0, stream>>>(flow, TEQ, TEK, TEV, TEO,
                                                             Wq, Wk, Wv, Wo, xtcn);
    g1_kernel<<<dim3(NB / 2, 3), 256, 0, stream>>>(flow, AdT, G1);
    final_kernel<<<dim3(NN, 64), 256, 0, stream>>>(xtcn, G1, Wg, Wt, bg, W1, b1, W2, b2,
                                                   ncnt, nidx, nw, out);
}

// Round 8
// 271.608 us; speedup vs baseline: 1.4814x; 1.0480x over previous
//
#include <hip/hip_runtime.h>
#include <hip/hip_bf16.h>
#include <math.h>

// ---- problem constants ----
#define NB 256      // batch
#define NN 307      // vertices
#define NBN 78592   // NB*NN
#define LL 12       // sequence length
#define DDIM 16     // model dim
#define HISW 268    // 267 history cols + 1 zero pad (for float4)
#define HIS4 67     // HISW/4
#define NBRCAP 64   // per-row neighbor capacity (mean 9.2, 64 is ~18 sigma)
#define AGRP 16     // bn rows per 192-thread attn block: stage B = 2 full waves
#define ADTS 308    // AdT row stride (padded even for float2 alignment)

// ---- workspace layout (float offsets; every segment 16B-aligned) ----
#define OFF_XTCN 0u            // 15089664 ushorts [B,N,L,D] bf16
#define OFF_G1   15089664u     //   943104 floats  [B,N,L]
#define OFF_ADT  16032768u     //    94688 floats  A_dyn^T [m][308]
#define OFF_TEQ  16127456u     //    49152 floats  [B,L,16]  (te@Wq+bq)/sqrt2
#define OFF_HIS  16176608u     //    82288 floats  [N,268]; TEK overlays (adyn first)
#define OFF_TEK  16176608u     //    49152 floats  te@Wk+bk   (aliases HIS)
#define OFF_NW   16258896u     //    19648 floats  nbr weights [N,64]
#define OFF_NIDX 16278544u     //    19648 ints    nbr indices [N,64]
#define OFF_NCNT 16298192u     //      320 ints    nbr counts
#define OFF_TEV  16298512u     //    49152 floats  te@Wv+bv
#define OFF_TEO  16347664u     //    49152 floats  te+bo

__device__ inline float4 mkf4(float a, float b, float c, float d) {
    float4 r; r.x = a; r.y = b; r.z = c; r.w = d; return r;
}

// ---------------------------------------------------------------------------
// K0a: build padded history matrix his[N][268]
// ---------------------------------------------------------------------------
__global__ void his_kernel(const float* __restrict__ flow, float* __restrict__ his) {
    int e = blockIdx.x * 256 + threadIdx.x;
    if (e >= NN * HISW) return;
    int n = e / HISW, j = e - n * HISW;
    float v = 0.f;
    if (j < LL) v = flow[n * LL + j];
    else if (j < 267) v = flow[((j - 11) * NN + n) * LL + 11];
    his[e] = v;
}

// ---------------------------------------------------------------------------
// K0b v2: TE tables. Row (b,l): te = pe + day_emb + week_emb, then
//   TEQ = (te@Wq+bq)/sqrt2, TEK = te@Wk+bk, TEV = te@Wv+bv, TEO = te+bo.
// ---------------------------------------------------------------------------
__global__ __launch_bounds__(256) void te_kernel(
    const int* __restrict__ dayc, const int* __restrict__ weekc,
    const float* __restrict__ demb, const float* __restrict__ wemb,
    const float* __restrict__ Wq, const float* __restrict__ bq,
    const float* __restrict__ Wk, const float* __restrict__ bk,
    const float* __restrict__ Wv, const float* __restrict__ bv,
    const float* __restrict__ bo,
    float* __restrict__ TEQ, float* __restrict__ TEK,
    float* __restrict__ TEV, float* __restrict__ TEO) {
    __shared__ float sTE[16][16];
    int t = threadIdx.x, r = t >> 4, d = t & 15;
    int row = blockIdx.x * 16 + r;            // row < NB*LL = 3072
    int b = row / LL, l = row - b * LL;
    int dc = dayc[b * LL + l], wc = weekc[b * LL + l];
    int i = d >> 1;
    float ang = (float)l * powf(10000.f, -0.125f * (float)i);
    float pe = (d & 1) ? cosf(ang) : sinf(ang);
    float te = demb[dc * DDIM + d] + wemb[wc * DDIM + d] + pe;
    sTE[r][d] = te;
    __syncthreads();
    float aq = bq[d], ak = bk[d], av = bv[d];
#pragma unroll
    for (int e = 0; e < 16; e++) {
        float x = sTE[r][e];
        aq += x * Wq[e * 16 + d];
        ak += x * Wk[e * 16 + d];
        av += x * Wv[e * 16 + d];
    }
    TEQ[row * 16 + d] = aq * 0.70710678118654752f;
    TEK[row * 16 + d] = ak;
    TEV[row * 16 + d] = av;
    TEO[row * 16 + d] = te + bo[d];
}

// ---------------------------------------------------------------------------
// K1: A_dyn row-softmax of -dist, stored transposed AdT[m*308+n]
// ---------------------------------------------------------------------------
__global__ __launch_bounds__(256) void adyn_kernel(const float* __restrict__ his,
                                                   float* __restrict__ AdT) {
    __shared__ float4 sh[HIS4];
    __shared__ float red[256];
    int n = blockIdx.x, t = threadIdx.x;
    if (t < HIS4) sh[t] = reinterpret_cast<const float4*>(his)[n * HIS4 + t];
    __syncthreads();

    float e0 = 0.f, e1 = 0.f, lsum = 0.f;
    {
        const float4* row = reinterpret_cast<const float4*>(his) + t * HIS4;
        float4 acc = mkf4(0.f, 0.f, 0.f, 0.f);
        for (int j = 0; j < HIS4; j++) {
            float4 a = sh[j], b = row[j];
            float dx = a.x - b.x, dy = a.y - b.y, dz = a.z - b.z, dw = a.w - b.w;
            acc.x += dx * dx; acc.y += dy * dy; acc.z += dz * dz; acc.w += dw * dw;
        }
        float d2 = (acc.x + acc.y) + (acc.z + acc.w);
        e0 = __expf(-sqrtf(fmaxf(d2, 0.f)));
        lsum += e0;
    }
    int m1 = t + 256;
    if (m1 < NN) {
        const float4* row = reinterpret_cast<const float4*>(his) + m1 * HIS4;
        float4 acc = mkf4(0.f, 0.f, 0.f, 0.f);
        for (int j = 0; j < HIS4; j++) {
            float4 a = sh[j], b = row[j];
            float dx = a.x - b.x, dy = a.y - b.y, dz = a.z - b.z, dw = a.w - b.w;
            acc.x += dx * dx; acc.y += dy * dy; acc.z += dz * dz; acc.w += dw * dw;
        }
        float d2 = (acc.x + acc.y) + (acc.z + acc.w);
        e1 = __expf(-sqrtf(fmaxf(d2, 0.f)));
        lsum += e1;
    }
    red[t] = lsum;
    __syncthreads();
    for (int s = 128; s > 0; s >>= 1) {
        if (t < s) red[t] += red[t + s];
        __syncthreads();
    }
    float inv = 1.f / red[0];
    AdT[t * ADTS + n] = e0 * inv;
    if (m1 < NN) AdT[m1 * ADTS + n] = e1 * inv;
}

// ---------------------------------------------------------------------------
// K2: sparse A_st rows (ballot compaction)
// ---------------------------------------------------------------------------
__global__ __launch_bounds__(64) void nbr_kernel(const float* __restrict__ adj,
                                                 int* __restrict__ ncnt,
                                                 int* __restrict__ nidx,
                                                 float* __restrict__ nw) {
    int n = blockIdx.x, t = threadIdx.x;
    float rs = 0.f;
    for (int m0 = 0; m0 < NN; m0 += 64) {
        int m = m0 + t;
        if (m < NN) rs += adj[n * NN + m];
    }
    for (int off = 32; off > 0; off >>= 1) rs += __shfl_xor(rs, off);
    float inv = 1.f / (rs + 1.f);
    int c = 0;
    for (int m0 = 0; m0 < NN; m0 += 64) {
        int m = m0 + t;
        float a = (m < NN) ? adj[n * NN + m] : 0.f;
        bool p = (a != 0.f);
        unsigned long long mask = __ballot(p);
        int pos = __popcll(mask & ((1ull << t) - 1ull));
        if (p && (c + pos) < NBRCAP) {
            nidx[n * NBRCAP + c + pos] = m;
            nw[n * NBRCAP + c + pos] = a * inv;
        }
        c += (int)__popcll(mask);
    }
    if (t == 0) ncnt[n] = c < NBRCAP ? c : NBRCAP;
}

// ---------------------------------------------------------------------------
// K3 v8: temporal self-attention, head-lane formulation + LDS-staged TE.
// AGRP=16, 192 threads: stage B = lanes (g,h) = 128 = exactly 2 waves;
// stage C = lanes (g,l) = 192 = all 3 waves. The block's <=2 batches' TE
// tables (TEQ/TEK/TEV/TEO, 6KB) are staged in LDS once, so stage B's 36
// per-lane global L2 loads (latency-bound in v7) become ~6-cyc LDS
// broadcasts. No K/V/Q LDS; only att crosses lanes (sA, self-owned slots).
// ---------------------------------------------------------------------------
__global__ __launch_bounds__(192) void attn_kernel(
    const float* __restrict__ flow,
    const float* __restrict__ TEQ, const float* __restrict__ TEK,
    const float* __restrict__ TEV, const float* __restrict__ TEO,
    const float* __restrict__ Wq, const float* __restrict__ Wk,
    const float* __restrict__ Wv, const float* __restrict__ Wo,
    unsigned short* __restrict__ xtcn) {
    __shared__ __align__(16) float sWo[256];
    __shared__ __align__(16) float sWs[48];   // wq1/sqrt2, wk1, wv1 col-sums
    __shared__ __align__(16) float sT[4][24][16];  // TEQ/TEK/TEV/TEO, 2 b's
    __shared__ __align__(16) float sA[AGRP][LL][20];

    const int t = threadIdx.x;
    const int bn0 = blockIdx.x * AGRP;
    const int b0 = bn0 / NN;
    const int rbase = b0 * LL;

    for (int id = t; id < 256; id += 192) sWo[id] = Wo[id];
    if (t < 48) {
        int mat = t >> 4, d = t & 15;
        const float* W = (mat == 0) ? Wq : (mat == 1) ? Wk : Wv;
        float s = 0.f;
#pragma unroll
        for (int e = 0; e < 16; e++) s += W[e * 16 + d];
        sWs[t] = (mat == 0) ? s * 0.70710678118654752f : s;
    }
    // stage TE tables: 4 tables x 24 rows x 16 floats = 384 float4 chunks
#pragma unroll
    for (int p = 0; p < 2; p++) {
        int idx = t + p * 192;
        int tab = idx / 96, rr4 = idx - tab * 96;
        int rr = rr4 >> 2, j = rr4 & 3;
        int row = rbase + rr;
        if (row < NB * LL) {
            const float* src = (tab == 0) ? TEQ : (tab == 1) ? TEK : (tab == 2) ? TEV : TEO;
            reinterpret_cast<float4*>(&sT[tab][rr][0])[j] =
                reinterpret_cast<const float4*>(src + row * 16)[j];
        }
    }
    __syncthreads();

    // ---- stage B: lanes (g,h), exactly 2 waves ----
    if (t < AGRP * 8) {
        int g = t >> 3, h = t & 7;
        int bn = bn0 + g;                  // < NBN always (AGRP divides NBN)
        int b = bn / NN;
        int lb = (b - b0) * LL;
        float f[12];
        {
            const float4* fr = reinterpret_cast<const float4*>(flow + bn * LL);
            float4 f0 = fr[0], f1 = fr[1], f2 = fr[2];
            f[0] = f0.x; f[1] = f0.y; f[2] = f0.z; f[3] = f0.w;
            f[4] = f1.x; f[5] = f1.y; f[6] = f1.z; f[7] = f1.w;
            f[8] = f2.x; f[9] = f2.y; f[10] = f2.z; f[11] = f2.w;
        }
        float wqx = sWs[2 * h], wqy = sWs[2 * h + 1];
        float wkx = sWs[16 + 2 * h], wky = sWs[16 + 2 * h + 1];
        float wvx = sWs[32 + 2 * h], wvy = sWs[32 + 2 * h + 1];
        float kx[12], ky[12], vx[12], vy[12];
#pragma unroll
        for (int m = 0; m < LL; m++) {
            float2 tk = *reinterpret_cast<const float2*>(&sT[1][lb + m][2 * h]);
            float2 tv = *reinterpret_cast<const float2*>(&sT[2][lb + m][2 * h]);
            kx[m] = tk.x + f[m] * wkx; ky[m] = tk.y + f[m] * wky;
            vx[m] = tv.x + f[m] * wvx; vy[m] = tv.y + f[m] * wvy;
        }
#pragma unroll
        for (int l = 0; l < LL; l++) {
            float2 tq = *reinterpret_cast<const float2*>(&sT[0][lb + l][2 * h]);
            float qx = tq.x + f[l] * wqx, qy = tq.y + f[l] * wqy;
            float s[12];
            float sum = 0.f;
#pragma unroll
            for (int m = 0; m < LL; m++) {
                s[m] = __expf(qx * kx[m] + qy * ky[m]);  // 1/sqrt2 folded into q
                sum += s[m];
            }
            float a0 = 0.f, a1 = 0.f;
#pragma unroll
            for (int m = 0; m < LL; m++) { a0 += s[m] * vx[m]; a1 += s[m] * vy[m]; }
            float inv = 1.f / sum;
            float2 r; r.x = a0 * inv; r.y = a1 * inv;
            *reinterpret_cast<float2*>(&sA[g][l][2 * h]) = r;
        }
    }
    __syncthreads();

    // ---- stage C: lanes (g,l), all 192 ----
    {
        int g = t / LL, l = t - g * LL;
        int bn = bn0 + g;
        int b = bn / NN;
        int lb = (b - b0) * LL;
        float f = flow[bn * LL + l];
        float att[16];
        const float4* ar = reinterpret_cast<const float4*>(&sA[g][l][0]);
        float4 a0 = ar[0], a1 = ar[1], a2 = ar[2], a3 = ar[3];
        att[0] = a0.x; att[1] = a0.y; att[2] = a0.z; att[3] = a0.w;
        att[4] = a1.x; att[5] = a1.y; att[6] = a1.z; att[7] = a1.w;
        att[8] = a2.x; att[9] = a2.y; att[10] = a2.z; att[11] = a2.w;
        att[12] = a3.x; att[13] = a3.y; att[14] = a3.z; att[15] = a3.w;
        float o[16];
        const float4* to4 = reinterpret_cast<const float4*>(&sT[3][lb + l][0]);
#pragma unroll
        for (int j = 0; j < 4; j++) {
            float4 a = to4[j];
            o[4 * j] = a.x; o[4 * j + 1] = a.y; o[4 * j + 2] = a.z; o[4 * j + 3] = a.w;
        }
#pragma unroll
        for (int e = 0; e < 16; e++) {
            float ae = att[e];
            const float4* wo = reinterpret_cast<const float4*>(&sWo[e * 16]);
#pragma unroll
            for (int j = 0; j < 4; j++) {
                float4 w = wo[j];
                o[4 * j] += ae * w.x; o[4 * j + 1] += ae * w.y;
                o[4 * j + 2] += ae * w.z; o[4 * j + 3] += ae * w.w;
            }
        }
        unsigned pk[8];
#pragma unroll
        for (int j = 0; j < 8; j++) {
            unsigned u0 = __float_as_uint(o[2 * j] + f) + 0x8000u;
            unsigned u1 = __float_as_uint(o[2 * j + 1] + f) + 0x8000u;
            pk[j] = (u0 >> 16) | (u1 & 0xffff0000u);
        }
        uint4* dst = reinterpret_cast<uint4*>(xtcn + (size_t)bn * 192 + l * 16);
        uint4 d0; d0.x = pk[0]; d0.y = pk[1]; d0.z = pk[2]; d0.w = pk[3];
        uint4 d1; d1.x = pk[4]; d1.y = pk[5]; d1.z = pk[6]; d1.w = pk[7];
        dst[0] = d0; dst[1] = d1;
    }
}

// ---------------------------------------------------------------------------
// K4 v4: G1 = A_dyn @ flow[b], 2 batches per block; flow via scalar loads.
// ---------------------------------------------------------------------------
__global__ __launch_bounds__(256) void g1_kernel(const float* __restrict__ flow,
                                                 const float* __restrict__ AdT,
                                                 float* __restrict__ G1) {
    int bp = blockIdx.x, nt = blockIdx.y, t = threadIdx.x;
    int lane = t & 63;
    int l0 = (t >> 6) * 3;
    int l0u = __builtin_amdgcn_readfirstlane(l0);
    int n = nt * 128 + 2 * lane;
    int b0 = 2 * bp;
    const float* fb0 = flow + (size_t)b0 * (NN * LL);
    const float* fb1 = fb0 + NN * LL;

    float a000 = 0.f, a001 = 0.f, a002 = 0.f;
    float a010 = 0.f, a011 = 0.f, a012 = 0.f;
    float a100 = 0.f, a101 = 0.f, a102 = 0.f;
    float a110 = 0.f, a111 = 0.f, a112 = 0.f;
#pragma unroll 4
    for (int m = 0; m < NN; m++) {
        float2 w = reinterpret_cast<const float2*>(AdT + (size_t)m * ADTS + nt * 128)[lane];
        const float* r0 = fb0 + m * LL + l0u;
        const float* r1 = fb1 + m * LL + l0u;
        float p0 = r0[0], p1 = r0[1], p2 = r0[2];
        float q0 = r1[0], q1 = r1[1], q2 = r1[2];
        a000 += w.x * p0; a001 += w.x * p1; a002 += w.x * p2;
        a010 += w.y * p0; a011 += w.y * p1; a012 += w.y * p2;
        a100 += w.x * q0; a101 += w.x * q1; a102 += w.x * q2;
        a110 += w.y * q0; a111 += w.y * q1; a112 += w.y * q2;
    }
    if (n < NN) {
        float* d0 = G1 + ((size_t)b0 * NN + n) * LL + l0;
        d0[0] = a000; d0[1] = a001; d0[2] = a002;
        float* d1 = G1 + ((size_t)(b0 + 1) * NN + n) * LL + l0;
        d1[0] = a100; d1[1] = a101; d1[2] = a102;
    }
    if (n + 1 < NN) {
        float* d0 = G1 + ((size_t)b0 * NN + n + 1) * LL + l0;
        d0[0] = a010; d0[1] = a011; d0[2] = a012;
        float* d1 = G1 + ((size_t)(b0 + 1) * NN + n + 1) * LL + l0;
        d1[0] = a110; d1[1] = a111; d1[2] = a112;
    }
}

// ---------------------------------------------------------------------------
// K5 v6: fused graph-mix + per-vertex MLP (v5 + gather unrolled x4 for MLP/
// memory-level parallelism over the ~9.2-neighbor chain).
// ---------------------------------------------------------------------------
__global__ __launch_bounds__(256) void final_kernel(
    const unsigned short* __restrict__ xtcn, const float* __restrict__ G1,
    const float* __restrict__ Wg, const float* __restrict__ Wt,
    const float* __restrict__ bg, const float* __restrict__ W1,
    const float* __restrict__ b1, const float* __restrict__ W2,
    const float* __restrict__ b2, const int* __restrict__ ncnt,
    const int* __restrict__ nidx, const float* __restrict__ nw,
    float* __restrict__ out) {
    __shared__ __align__(16) float sWt[512];
    __shared__ __align__(16) float sW1[256];
    __shared__ __align__(16) float sWg[32];
    __shared__ __align__(16) float sBg[32];
    __shared__ float sB1[8], sW2[8];
    __shared__ __align__(16) float sY[4][240];      // stride 20 per l
    __shared__ __align__(16) float4 sHID[4][120];   // stride 10 float4 per l
    __shared__ float sH1[4][96];

    int t = threadIdx.x;
    int n = blockIdx.x;
    int w = t >> 6, t64 = t & 63;
    int b = blockIdx.y * 4 + w;

    // stage weights
    sW1[t] = W1[n * 256 + t];
    sWt[t] = Wt[t];
    sWt[t + 256] = Wt[t + 256];
    if (t < 32) sWg[t] = Wg[t];
    else if (t < 64) sBg[t - 32] = bg[t - 32];
    else if (t < 72) sB1[t - 64] = b1[n * 8 + (t - 64)];
    else if (t < 80) sW2[t - 72] = W2[n * 8 + (t - 72)];
    float vb2 = b2[n];
    int cnt = ncnt[n];
    __syncthreads();

    // sparse gather (bf16): lane t64<48 owns elements 4*t64 .. 4*t64+3
    if (t64 < 48) {
        float y0 = 0.f, y1 = 0.f, y2 = 0.f, y3 = 0.f;
        const unsigned short* base = xtcn + (size_t)b * NN * 192;
        int i = 0;
        for (; i + 3 < cnt; i += 4) {
            int m0 = nidx[n * NBRCAP + i],     m1 = nidx[n * NBRCAP + i + 1];
            int m2 = nidx[n * NBRCAP + i + 2], m3 = nidx[n * NBRCAP + i + 3];
            float w0 = nw[n * NBRCAP + i],     w1 = nw[n * NBRCAP + i + 1];
            float w2 = nw[n * NBRCAP + i + 2], w3 = nw[n * NBRCAP + i + 3];
            uint2 p0 = reinterpret_cast<const uint2*>(base + m0 * 192)[t64];
            uint2 p1 = reinterpret_cast<const uint2*>(base + m1 * 192)[t64];
            uint2 p2 = reinterpret_cast<const uint2*>(base + m2 * 192)[t64];
            uint2 p3 = reinterpret_cast<const uint2*>(base + m3 * 192)[t64];
            y0 += w0 * __uint_as_float(p0.x << 16) + w1 * __uint_as_float(p1.x << 16)
                + w2 * __uint_as_float(p2.x << 16) + w3 * __uint_as_float(p3.x << 16);
            y1 += w0 * __uint_as_float(p0.x & 0xffff0000u) + w1 * __uint_as_float(p1.x & 0xffff0000u)
                + w2 * __uint_as_float(p2.x & 0xffff0000u) + w3 * __uint_as_float(p3.x & 0xffff0000u);
            y2 += w0 * __uint_as_float(p0.y << 16) + w1 * __uint_as_float(p1.y << 16)
                + w2 * __uint_as_float(p2.y << 16) + w3 * __uint_as_float(p3.y << 16);
            y3 += w0 * __uint_as_float(p0.y & 0xffff0000u) + w1 * __uint_as_float(p1.y & 0xffff0000u)
                + w2 * __uint_as_float(p2.y & 0xffff0000u) + w3 * __uint_as_float(p3.y & 0xffff0000u);
        }
        for (; i < cnt; i++) {
            int ma = nidx[n * NBRCAP + i];
            float wa = nw[n * NBRCAP + i];
            uint2 pa = reinterpret_cast<const uint2*>(base + ma * 192)[t64];
            y0 += wa * __uint_as_float(pa.x << 16);
            y1 += wa * __uint_as_float(pa.x & 0xffff0000u);
            y2 += wa * __uint_as_float(pa.y << 16);
            y3 += wa * __uint_as_float(pa.y & 0xffff0000u);
        }
        int l = t64 >> 2, p = (t64 & 3);
        reinterpret_cast<float4*>(&sY[w][l * 20])[p] = mkf4(y0, y1, y2, y3);
    }
    __syncthreads();

    // hid = relu(G1*Wg + y@Wt + bg): 384 jobs over 256 lanes
#pragma unroll
    for (int p = 0; p < 2; p++) {
        int jb = t + p * 256;
        if (jb < 384) {
            int w2 = jb / 96, c = jb - w2 * 96;
            int b2i = blockIdx.y * 4 + w2;
            int l = c >> 3, j = c & 7;
            float g = G1[((size_t)b2i * NN + n) * LL + l];
            float4 wg = reinterpret_cast<const float4*>(sWg)[j];
            float4 acc = reinterpret_cast<const float4*>(sBg)[j];
            acc.x += g * wg.x; acc.y += g * wg.y; acc.z += g * wg.z; acc.w += g * wg.w;
            const float4* yr = reinterpret_cast<const float4*>(&sY[w2][l * 20]);
            float4 v0 = yr[0], v1 = yr[1], v2 = yr[2], v3 = yr[3];
            float ye[16] = {v0.x, v0.y, v0.z, v0.w, v1.x, v1.y, v1.z, v1.w,
                            v2.x, v2.y, v2.z, v2.w, v3.x, v3.y, v3.z, v3.w};
#pragma unroll
            for (int d = 0; d < 16; d++) {
                float4 wt = reinterpret_cast<const float4*>(sWt)[d * 8 + j];
                acc.x += ye[d] * wt.x; acc.y += ye[d] * wt.y;
                acc.z += ye[d] * wt.z; acc.w += ye[d] * wt.w;
            }
            acc.x = fmaxf(acc.x, 0.f); acc.y = fmaxf(acc.y, 0.f);
            acc.z = fmaxf(acc.z, 0.f); acc.w = fmaxf(acc.w, 0.f);
            sHID[w2][l * 10 + j] = acc;
        }
    }
    __syncthreads();

    // h1 = relu(hid @ W1[n] + b1[n]): 384 jobs over 256 lanes
#pragma unroll
    for (int p = 0; p < 2; p++) {
        int jb = t + p * 256;
        if (jb < 384) {
            int w2 = jb / 96, o = jb - w2 * 96;
            int l = o >> 3, oo = o & 7;
            float acc = sB1[oo];
            float he[32];
#pragma unroll
            for (int k = 0; k < 8; k++) {
                float4 hv = sHID[w2][l * 10 + k];
                he[4 * k + 0] = hv.x; he[4 * k + 1] = hv.y;
                he[4 * k + 2] = hv.z; he[4 * k + 3] = hv.w;
            }
#pragma unroll
            for (int c = 0; c < 32; c++) acc += he[c] * sW1[c * 8 + oo];
            sH1[w2][o] = fmaxf(acc, 0.f);
        }
    }
    __syncthreads();

    // out = h1 @ W2[n] + b2[n]: 48 jobs
    if (t < 48) {
        int w2 = t / 12, l = t - w2 * 12;
        int b2i = blockIdx.y * 4 + w2;
        float acc = vb2;
#pragma unroll
        for (int o = 0; o < 8; o++) acc += sH1[w2][l * 8 + o] * sW2[o];
        out[((size_t)b2i * NN + n) * LL + l] = acc;
    }
}

// ---------------------------------------------------------------------------
extern "C" void kernel_launch(void* const* d_in, const int* in_sizes, int n_in,
                              void* d_out, int out_size, void* d_ws, size_t ws_size,
                              hipStream_t stream) {
    const float* flow = (const float*)d_in[0];
    const int* dayc   = (const int*)d_in[1];
    const int* weekc  = (const int*)d_in[2];
    const float* adj  = (const float*)d_in[3];
    const float* demb = (const float*)d_in[4];
    const float* wemb = (const float*)d_in[5];
    const float* Wq = (const float*)d_in[6];  const float* bq = (const float*)d_in[7];
    const float* Wk = (const float*)d_in[8];  const float* bk = (const float*)d_in[9];
    const float* Wv = (const float*)d_in[10]; const float* bv = (const float*)d_in[11];
    const float* Wo = (const float*)d_in[12]; const float* bo = (const float*)d_in[13];
    const float* Wg = (const float*)d_in[14]; const float* Wt = (const float*)d_in[15];
    const float* bg = (const float*)d_in[16];
    const float* W1 = (const float*)d_in[17]; const float* b1 = (const float*)d_in[18];
    const float* W2 = (const float*)d_in[19]; const float* b2 = (const float*)d_in[20];
    float* out = (float*)d_out;
    float* ws  = (float*)d_ws;

    unsigned short* xtcn = (unsigned short*)(ws + 0);   // bf16 region
    float* G1   = ws + OFF_G1;
    float* AdT  = ws + OFF_ADT;
    float* TEQ  = ws + OFF_TEQ;
    float* TEK  = ws + OFF_TEK;   // overlays his (adyn runs first)
    float* TEV  = ws + OFF_TEV;
    float* TEO  = ws + OFF_TEO;
    float* his  = ws + OFF_HIS;
    float* nw   = ws + OFF_NW;
    int*   nidx = (int*)(ws + OFF_NIDX);
    int*   ncnt = (int*)(ws + OFF_NCNT);

    // his -> adyn first (TEK overlays the his buffer afterwards)
    his_kernel<<<(NN * HISW + 255) / 256, 256, 0, stream>>>(flow, his);
    adyn_kernel<<<NN, 256, 0, stream>>>(his, AdT);
    te_kernel<<<(NB * LL) / 16, 256, 0, stream>>>(dayc, weekc, demb, wemb,
                                                  Wq, bq, Wk, bk, Wv, bv, bo,
                                                  TEQ, TEK, TEV, TEO);
    nbr_kernel<<<NN, 64, 0, stream>>>(adj, ncnt, nidx, nw);
    attn_kernel<<<NBN / AGRP, 192, 0, stream>>>(flow, TEQ, TEK, TEV, TEO,
                                                Wq, Wk, Wv, Wo, xtcn);
    g1_kernel<<<dim3(NB / 2, 3), 256, 0, stream>>>(flow, AdT, G1);
    final_kernel<<<dim3(NN, 64), 256, 0, stream>>>(xtcn, G1, Wg, Wt, bg, W1, b1, W2, b2,
                                                   ncnt, nidx, nw, out);
}